// Round 8
// baseline (324.315 us; speedup 1.0000x reference)
//
#include <hip/hip_runtime.h>
#include <math.h>

// ---------------- workspace layout ----------------
#define WS_POS   0
#define WS_LSE   1
#define WS_ACC2  2
#define WS_ACC3  3
#define WS_S2    256
#define WS_S3    (256+25600)
#define WS_SEG   163840
#define NROWS    144                 // 112 padded l2 rows + 32 padded l3 rows
#define PART_FLOATS (NROWS*256 + 128)  // 36992; counts at [36864, 36984)
#define PIMG_BYTE_OFF 131072

#define SC2  14.426950408889634f    // (1/TEMP=10) * log2(e)
#define BIAS 48.0f

typedef __attribute__((ext_vector_type(4))) float f32x4;
typedef __attribute__((ext_vector_type(8))) short short8;

static __device__ __forceinline__ unsigned f2bf(float f) {
    union { float f; unsigned u; } x; x.f = f;
    unsigned r = x.u + 0x7FFFu + ((x.u >> 16) & 1u);   // RNE
    return r >> 16;
}

// ---------------- generic zero ----------------
__global__ void k_zero(float* __restrict__ p, int count) {
    int i = blockIdx.x * 256 + threadIdx.x;
    if (i < count) p[i] = 0.f;
}

// ---------------- build plain bf16 proto image [1024][256], pad rows zero ----
// (also zeroes ws[0..256) from block 0 — saves a separate launch)
__global__ void k_prep(const float* __restrict__ p1, unsigned short* __restrict__ Pimg,
                       float* __restrict__ ws, int C1) {
    if (blockIdx.x == 0) ws[threadIdx.x] = 0.f;
    int e = blockIdx.x * 256 + threadIdx.x;   // 32768 threads, 8 elems each
    int r  = e >> 5;
    int k0 = (e & 31) * 8;
    unsigned h[8];
#pragma unroll
    for (int j = 0; j < 8; ++j)
        h[j] = (r < C1) ? f2bf(p1[(size_t)r * 256 + k0 + j]) : 0u;
    uint4 v;
    v.x = h[0] | (h[1] << 16);
    v.y = h[2] | (h[3] << 16);
    v.z = h[4] | (h[5] << 16);
    v.w = h[6] | (h[7] << 16);
    *(uint4*)(Pimg + (size_t)r * 256 + k0) = v;
}

// ---------------- segment sums as one-hot MFMA GEMM + fine positive dot -----
__global__ __launch_bounds__(256, 2) void k_seg(
        const float* __restrict__ feat, const float* __restrict__ p1,
        const int* __restrict__ l1, const int* __restrict__ l2,
        const int* __restrict__ l3, float* __restrict__ ws,
        int partMask, int useAtomic) {
    __shared__ int labs23[512];   // l2 | l3<<16
    __shared__ int labs1[512];
    __shared__ float psum[4];
    const int tid  = threadIdx.x;
    const int lane = tid & 63;
    const int wv   = tid >> 6;          // 0..3
    const int g    = lane >> 4;         // 0..3 (k-group)
    const int rs   = lane & 15;
    const int chunk = blockIdx.x >> 1, half = blockIdx.x & 1;
    const int base  = chunk * 512;
    const int dimbase = half * 128 + wv * 32;

    for (int j = tid; j < 512; j += 256) {
        labs23[j] = l2[base + j] | (l3[base + j] << 16);
        labs1[j]  = l1[base + j];
    }
    __syncthreads();

    f32x4 acc[9][2];
#pragma unroll
    for (int mt = 0; mt < 9; ++mt)
#pragma unroll
        for (int nt = 0; nt < 2; ++nt) acc[mt][nt] = (f32x4){0.f, 0.f, 0.f, 0.f};

    float fA[16], pA[16], fB[16], pB[16];
    float posacc = 0.f;

#define LOADSTEP(u, F, P) { \
    const int sl0 = (u) * 32 + 8 * g; \
    _Pragma("unroll") \
    for (int j = 0; j < 8; ++j) { \
        const int sl = sl0 + j; \
        const size_t fb = (size_t)(base + sl) * 256 + dimbase + rs; \
        F[j]     = feat[fb]; \
        F[8 + j] = feat[fb + 16]; \
        const size_t pb = (size_t)labs1[sl] * 256 + dimbase + rs; \
        P[j]     = p1[pb]; \
        P[8 + j] = p1[pb + 16]; \
    } }

#define PROCSTEP(u, F, P) { \
    _Pragma("unroll") \
    for (int j = 0; j < 16; ++j) posacc = fmaf(F[j], P[j], posacc); \
    union { unsigned w[4]; short8 s; } b0, b1; \
    _Pragma("unroll") \
    for (int q = 0; q < 4; ++q) { \
        asm("v_cvt_pk_bf16_f32 %0, %1, %2" : "=v"(b0.w[q]) : "v"(F[2*q]),   "v"(F[2*q+1])); \
        asm("v_cvt_pk_bf16_f32 %0, %1, %2" : "=v"(b1.w[q]) : "v"(F[8+2*q]), "v"(F[8+2*q+1])); \
    } \
    int d2[8], d3[8]; \
    { const int sl0 = (u) * 32 + 8 * g; \
      _Pragma("unroll") \
      for (int j = 0; j < 8; ++j) { \
          const int v = labs23[sl0 + j]; \
          d2[j] = (v & 0xffff) - rs; \
          d3[j] = (v >> 16) - rs; \
      } } \
    _Pragma("unroll") \
    for (int mt = 0; mt < 7; ++mt) { \
        union { unsigned w[4]; short8 s; } af; \
        _Pragma("unroll") \
        for (int q = 0; q < 4; ++q) { \
            unsigned w = (d2[2*q] == mt*16) ? 0x3F80u : 0u; \
            if (d2[2*q+1] == mt*16) w |= 0x3F800000u; \
            af.w[q] = w; \
        } \
        acc[mt][0] = __builtin_amdgcn_mfma_f32_16x16x32_bf16(af.s, b0.s, acc[mt][0], 0, 0, 0); \
        acc[mt][1] = __builtin_amdgcn_mfma_f32_16x16x32_bf16(af.s, b1.s, acc[mt][1], 0, 0, 0); \
    } \
    _Pragma("unroll") \
    for (int mt = 0; mt < 2; ++mt) { \
        union { unsigned w[4]; short8 s; } af; \
        _Pragma("unroll") \
        for (int q = 0; q < 4; ++q) { \
            unsigned w = (d3[2*q] == mt*16) ? 0x3F80u : 0u; \
            if (d3[2*q+1] == mt*16) w |= 0x3F800000u; \
            af.w[q] = w; \
        } \
        acc[7+mt][0] = __builtin_amdgcn_mfma_f32_16x16x32_bf16(af.s, b0.s, acc[7+mt][0], 0, 0, 0); \
        acc[7+mt][1] = __builtin_amdgcn_mfma_f32_16x16x32_bf16(af.s, b1.s, acc[7+mt][1], 0, 0, 0); \
    } }

    LOADSTEP(0, fA, pA);
#pragma unroll 1
    for (int t = 0; t < 16; t += 2) {
        LOADSTEP(t + 1, fB, pB);
        PROCSTEP(t, fA, pA);
        if (t + 2 < 16) LOADSTEP(t + 2, fA, pA);
        PROCSTEP(t + 1, fB, pB);
    }
#undef LOADSTEP
#undef PROCSTEP

    // ---- epilogue: write partials. row = mt*16 + 4*g + r, col = dim ----
    float* part = ws + WS_SEG +
        (size_t)(useAtomic ? (chunk & partMask) : chunk) * PART_FLOATS;
#pragma unroll
    for (int mt = 0; mt < 9; ++mt)
#pragma unroll
        for (int nt = 0; nt < 2; ++nt)
#pragma unroll
            for (int r = 0; r < 4; ++r) {
                float v = acc[mt][nt][r];
                float* dst = &part[(mt * 16 + 4 * g + r) * 256 + dimbase + nt * 16 + rs];
                if (useAtomic) atomicAdd(dst, v); else *dst = v;
            }

    // ---- per-class counts (half 0 only) ----
    if (half == 0 && tid < 120) {
        float cnt = 0.f;
        const int isl2 = tid < 100;
        const int cls = isl2 ? tid : tid - 100;
#pragma unroll 8
        for (int j = 0; j < 512; ++j) {
            int v = labs23[j];
            int lab = isl2 ? (v & 0xffff) : (v >> 16);
            cnt += (lab == cls) ? 1.f : 0.f;
        }
        float* dst = &part[NROWS * 256 + tid];
        if (useAtomic) atomicAdd(dst, cnt); else *dst = cnt;
    }

    // ---- reduce positive dot ----
#pragma unroll
    for (int m = 1; m < 64; m <<= 1) posacc += __shfl_xor(posacc, m);
    if (lane == 0) psum[wv] = posacc;
    __syncthreads();
    if (tid == 0) atomicAdd(&ws[WS_POS], psum[0] + psum[1] + psum[2] + psum[3]);
}

// ---------------- partials -> means (one block per class row) ----------------
__global__ __launch_bounds__(256, 4) void k_div(float* __restrict__ ws, int npart) {
    __shared__ float cred[4];
    const int c = blockIdx.x;             // 0..119
    const int d = threadIdx.x;            // dim
    const int prow = (c < 100) ? c : 112 + (c - 100);
    float cv = (d < npart) ? ws[WS_SEG + (size_t)d * PART_FLOATS + NROWS * 256 + c] : 0.f;
#pragma unroll
    for (int m = 1; m < 64; m <<= 1) cv += __shfl_xor(cv, m);
    if ((d & 63) == 0) cred[d >> 6] = cv;
    __syncthreads();
    const float cnt = cred[0] + cred[1] + cred[2] + cred[3];
    float a0=0,a1=0,a2=0,a3=0,a4=0,a5=0,a6=0,a7=0;
    int p = 0;
    for (; p + 8 <= npart; p += 8) {
        const float* b = ws + WS_SEG + (size_t)p * PART_FLOATS + prow * 256 + d;
        a0 += b[0 * (size_t)PART_FLOATS];
        a1 += b[1 * (size_t)PART_FLOATS];
        a2 += b[2 * (size_t)PART_FLOATS];
        a3 += b[3 * (size_t)PART_FLOATS];
        a4 += b[4 * (size_t)PART_FLOATS];
        a5 += b[5 * (size_t)PART_FLOATS];
        a6 += b[6 * (size_t)PART_FLOATS];
        a7 += b[7 * (size_t)PART_FLOATS];
    }
    for (; p < npart; ++p)
        a0 += ws[WS_SEG + (size_t)p * PART_FLOATS + prow * 256 + d];
    const float s = ((a0+a1)+(a2+a3)) + ((a4+a5)+(a6+a7));
    ws[256 + ((c < 100) ? c * 256 : 25600 + (c - 100) * 256) + d] = s / cnt;
}

// ---- opaque B loads (r4/r7-proven): asm is not rematerializable, so loads
// issue exactly once where written and outputs stay register-resident.
#define LOADB(dst, ptr, OFF) \
    asm volatile("global_load_dwordx4 %0, %1, off offset:" #OFF \
                 : "=v"(dst) : "v"(ptr))
#define LOADB8(buf, ptr) \
    LOADB(buf[0], ptr, 0);   LOADB(buf[1], ptr, 64);  \
    LOADB(buf[2], ptr, 128); LOADB(buf[3], ptr, 192); \
    LOADB(buf[4], ptr, 256); LOADB(buf[5], ptr, 320); \
    LOADB(buf[6], ptr, 384); LOADB(buf[7], ptr, 448)

// ---------------- fine level: MFMA GEMM + in-register biased sum-exp --------
// 256-ROW tile (vs 128): halves B (Pimg) re-read traffic 512->256 MB chip-
// wide — the only lever left with a MEASURED cost coefficient (r2: +512 MB
// B traffic cost +56 us at constant per-wave structure). 512 thr (8 waves),
// Af = 128 KB LDS, 1 block/CU, 2 waves/SIMD (occupancy unchanged — proven
// irrelevant r0-r6). Per-CU MFMA/LDS/A-traffic totals unchanged. Single
// B buffer (no cross-pass prefetch): saves 64 VGPR vs r7's dbuf, costs
// 4 pass-head bubbles (~1%); VGPR ~180 < 256 cap of (512,2) — r5's spill
// failure mode is the thing to avoid.
__global__ __launch_bounds__(512, 2) void k_fine(
        const float* __restrict__ feat, const unsigned short* __restrict__ Pimg,
        float* __restrict__ ws, int C1) {
    __shared__ __align__(16) unsigned short Af[256 * 256];  // 128 KB, swizzled
    __shared__ float Sbuf[256];
    __shared__ float redl[8];
    const int tid  = threadIdx.x;
    const int lane = tid & 63;
    const int wv   = tid >> 6;        // 0..7
    const int g    = lane >> 4;       // 0..3
    const int rs   = lane & 15;
    const int row0 = blockIdx.x * 256;

#define PBP(p) ((const char*)Pimg + (size_t)((p) * 256 + wv * 32 + rs) * 512 + g * 16)

    // ---- issue pass-0 B loads first: they complete under the staging ----
    short8 bA[2][8];
    { const char* pb = PBP(0); LOADB8(bA[0], pb); LOADB8(bA[1], pb + 8192); }

    // ---- stage A: 8 floats/unit -> cvt_pk x4 -> ds_write_b128, swizzled ----
#pragma unroll
    for (int i = 0; i < 16; ++i) {
        int u = tid + i * 512;                 // 16B unit, 8192 total
        int r = u >> 5, q8 = u & 31;
        const float* src = feat + (size_t)(row0 + r) * 256 + q8 * 8;
        f32x4 v0 = *(const f32x4*)(src);
        f32x4 v1 = *(const f32x4*)(src + 4);
        uint4 pk;
        asm("v_cvt_pk_bf16_f32 %0, %1, %2" : "=v"(pk.x) : "v"(v0[0]), "v"(v0[1]));
        asm("v_cvt_pk_bf16_f32 %0, %1, %2" : "=v"(pk.y) : "v"(v0[2]), "v"(v0[3]));
        asm("v_cvt_pk_bf16_f32 %0, %1, %2" : "=v"(pk.z) : "v"(v1[0]), "v"(v1[1]));
        asm("v_cvt_pk_bf16_f32 %0, %1, %2" : "=v"(pk.w) : "v"(v1[2]), "v"(v1[3]));
        *(uint4*)((char*)Af + r * 512 + ((q8 * 16) ^ ((r & 7) << 4))) = pk;
    }
    if (tid < 256) Sbuf[tid] = 0.f;
    __syncthreads();   // compiler drains vmcnt here -> bA valid after barrier

    float es[16][4];
#pragma unroll
    for (int a = 0; a < 16; ++a)
#pragma unroll
        for (int b = 0; b < 4; ++b) es[a][b] = 0.f;

#pragma unroll 1
    for (int p = 0; p < 4; ++p) {
        asm volatile("s_waitcnt vmcnt(0)" ::: "memory");   // bA complete
        __builtin_amdgcn_sched_barrier(0);
#pragma unroll
        for (int rt = 0; rt < 16; ++rt) {
            f32x4 acc0 = (f32x4){0.f, 0.f, 0.f, 0.f};
            f32x4 acc1 = (f32x4){0.f, 0.f, 0.f, 0.f};
            const int ar = rt * 16 + rs;
            const char* abase = (const char*)Af + ar * 512;
            const int sw = (ar & 7) << 4;
#pragma unroll
            for (int ks = 0; ks < 8; ++ks) {
                short8 a = *(const short8*)(abase + ((ks * 64 + g * 16) ^ sw));
                acc0 = __builtin_amdgcn_mfma_f32_16x16x32_bf16(a, bA[0][ks], acc0, 0, 0, 0);
                acc1 = __builtin_amdgcn_mfma_f32_16x16x32_bf16(a, bA[1][ks], acc1, 0, 0, 0);
            }
            // ---- in-register epilogue: paired exp, one s_nop per 2 ----
#pragma unroll
            for (int r = 0; r < 4; ++r) {
                float t0 = fmaf(acc0[r], SC2, -BIAS);
                float t1 = fmaf(acc1[r], SC2, -BIAS);
                float e0, e1;
                asm("v_exp_f32 %0, %2\n\t"
                    "v_exp_f32 %1, %3\n\t"
                    "s_nop 1"
                    : "=&v"(e0), "=&v"(e1) : "v"(t0), "v"(t1));
                es[rt][r] += e0 + e1;
            }
        }
        // issue next pass's B loads (in-order issue: MFMAs above already
        // read the old bA values; WAR is safe, anti-dep kept post-RA)
        if (p + 1 < 4) {
            const char* pb = PBP(p + 1);
            LOADB8(bA[0], pb); LOADB8(bA[1], pb + 8192);
        }
    }
#undef PBP

    // ---- one reduction pass: row = rt*16 + 4*g + r ----
#pragma unroll
    for (int rt = 0; rt < 16; ++rt) {
#pragma unroll
        for (int r = 0; r < 4; ++r) {
            float e = es[rt][r];
            e += __shfl_xor(e, 1);
            e += __shfl_xor(e, 2);
            e += __shfl_xor(e, 4);
            e += __shfl_xor(e, 8);
            if (rs == 0) atomicAdd(&Sbuf[rt * 16 + 4 * g + r], e);
        }
    }
    __syncthreads();
    // ---- lse over the 256 rows (first 4 waves) ----
    if (tid < 256) {
        float S = Sbuf[tid] - (float)(1024 - C1) * exp2f(-BIAS);  // exact pad removal
        float lse = (BIAS + log2f(S)) * 0.6931471805599453f;
#pragma unroll
        for (int m = 1; m < 64; m <<= 1) lse += __shfl_xor(lse, m);
        if (lane == 0) redl[tid >> 6] = lse;
    }
    __syncthreads();
    if (tid == 0)
        atomicAdd(&ws[WS_LSE], (redl[0] + redl[1]) + (redl[2] + redl[3]));
}

// ---------------- proto-NCE on the means ----------------
__global__ __launch_bounds__(128, 4) void k_nce(
        const float* __restrict__ p2, const float* __restrict__ p3,
        float* __restrict__ ws) {
    __shared__ __align__(16) float mrow[256];
    __shared__ float sim[128];
    __shared__ float red[2];
    const int b = blockIdx.x;
    const float* means; const float* prot; int C, r, accIdx;
    if (b < 100) { means = ws + WS_S2; prot = p2; C = 100; r = b;       accIdx = WS_ACC2; }
    else         { means = ws + WS_S3; prot = p3; C = 20;  r = b - 100; accIdx = WS_ACC3; }
    const int tid = threadIdx.x;
    const int lane = tid & 63;
    mrow[tid]       = means[(size_t)r * 256 + tid];
    mrow[128 + tid] = means[(size_t)r * 256 + 128 + tid];
    __syncthreads();
    if (tid < C) {
        const f32x4* mr = (const f32x4*)mrow;
        const f32x4* pr = (const f32x4*)(prot + (size_t)tid * 256);
        float acc = 0.f;
#pragma unroll 4
        for (int k = 0; k < 64; ++k) {
            f32x4 m = mr[k], qv = pr[k];
            acc += m[0]*qv[0] + m[1]*qv[1] + m[2]*qv[2] + m[3]*qv[3];
        }
        sim[tid] = acc * 10.0f;
    }
    __syncthreads();
    float v = (tid < C) ? sim[tid] : -1e30f;
#pragma unroll
    for (int m = 1; m < 64; m <<= 1) v = fmaxf(v, __shfl_xor(v, m));
    if (lane == 0) red[tid >> 6] = v;
    __syncthreads();
    const float mx = fmaxf(red[0], red[1]);
    float e = (tid < C) ? __expf(sim[tid] - mx) : 0.f;
#pragma unroll
    for (int m = 1; m < 64; m <<= 1) e += __shfl_xor(e, m);
    __syncthreads();
    if (lane == 0) red[tid >> 6] = e;
    __syncthreads();
    if (tid == 0) {
        float lse = mx + logf(red[0] + red[1]);
        atomicAdd(&ws[accIdx], lse - sim[r]);
    }
}

// ---------------- finalize ----------------
__global__ void k_final(const float* __restrict__ ws, float* __restrict__ out, float Nf) {
    if (threadIdx.x == 0 && blockIdx.x == 0) {
        float fine   = (ws[WS_LSE] - 10.0f * ws[WS_POS]) / Nf;
        float coarse = ws[WS_ACC2] / 100.0f;
        float con    = ws[WS_ACC3] / 20.0f;
        out[0] = 0.5f * fine + 0.5f * coarse + 0.0f * con;
        out[1] = fine;
        out[2] = coarse;
        out[3] = con;
    }
}

extern "C" void kernel_launch(void* const* d_in, const int* in_sizes, int n_in,
                              void* d_out, int out_size, void* d_ws, size_t ws_size,
                              hipStream_t stream) {
    const float* feat = (const float*)d_in[0];
    const float* p1   = (const float*)d_in[1];
    const int*   l1   = (const int*)d_in[2];
    const float* p2   = (const float*)d_in[3];
    const int*   l2   = (const int*)d_in[4];
    const float* p3   = (const float*)d_in[5];
    const int*   l3   = (const int*)d_in[6];
    float* out = (float*)d_out;
    float* ws  = (float*)d_ws;
    const int n  = in_sizes[0] / 256;       // 131072
    const int c1 = in_sizes[1] / 256;       // 1000
    unsigned short* Pimg = (unsigned short*)((char*)d_ws + PIMG_BYTE_OFF);

    // adaptive partial-buffer count (nchunk = n/512 = 256)
    const int nchunk = n / 512;
    long nfull = ((long)(ws_size / 4) - WS_SEG) / PART_FLOATS;
    int useAtomic, npart;
    if (nfull >= nchunk) { useAtomic = 0; npart = nchunk; }
    else {
        useAtomic = 1;
        npart = 1;
        while (npart * 2 <= (int)nfull && npart < 32) npart <<= 1;
    }

    if (useAtomic)
        k_zero <<<(npart * PART_FLOATS + 255) / 256, 256, 0, stream>>>(ws + WS_SEG, npart * PART_FLOATS);
    k_prep <<<128, 256, 0, stream>>>(p1, Pimg, ws, c1);
    k_seg  <<<nchunk * 2, 256, 0, stream>>>(feat, p1, l1, l2, l3, ws, npart - 1, useAtomic);
    k_div  <<<120, 256, 0, stream>>>(ws, npart);
    k_fine <<<n / 256, 512, 0, stream>>>(feat, Pimg, ws, c1);
    k_nce  <<<120, 128, 0, stream>>>(p2, p3, ws);
    k_final<<<1, 64, 0, stream>>>(ws, out, (float)n);
}

// Round 9
// 318.443 us; speedup vs baseline: 1.0184x; 1.0184x over previous
//
#include <hip/hip_runtime.h>
#include <math.h>

// ---------------- workspace layout ----------------
#define WS_POS   0
#define WS_LSE   1
#define WS_ACC2  2
#define WS_ACC3  3
#define WS_S2    256
#define WS_S3    (256+25600)
#define WS_SEG   163840
#define NROWS    144                 // 112 padded l2 rows + 32 padded l3 rows
#define PART_FLOATS (NROWS*256 + 128)  // 36992; counts at [36864, 36984)
#define PIMG_BYTE_OFF 131072

#define SC2  14.426950408889634f    // (1/TEMP=10) * log2(e)
#define BIAS 48.0f

typedef __attribute__((ext_vector_type(4))) float f32x4;
typedef __attribute__((ext_vector_type(8))) short short8;

static __device__ __forceinline__ unsigned f2bf(float f) {
    union { float f; unsigned u; } x; x.f = f;
    unsigned r = x.u + 0x7FFFu + ((x.u >> 16) & 1u);   // RNE
    return r >> 16;
}

// ---------------- generic zero ----------------
__global__ void k_zero(float* __restrict__ p, int count) {
    int i = blockIdx.x * 256 + threadIdx.x;
    if (i < count) p[i] = 0.f;
}

// ---------------- build plain bf16 proto image [1024][256], pad rows zero ----
// (also zeroes ws[0..256) from block 0 — saves a separate launch)
__global__ void k_prep(const float* __restrict__ p1, unsigned short* __restrict__ Pimg,
                       float* __restrict__ ws, int C1) {
    if (blockIdx.x == 0) ws[threadIdx.x] = 0.f;
    int e = blockIdx.x * 256 + threadIdx.x;   // 32768 threads, 8 elems each
    int r  = e >> 5;
    int k0 = (e & 31) * 8;
    unsigned h[8];
#pragma unroll
    for (int j = 0; j < 8; ++j)
        h[j] = (r < C1) ? f2bf(p1[(size_t)r * 256 + k0 + j]) : 0u;
    uint4 v;
    v.x = h[0] | (h[1] << 16);
    v.y = h[2] | (h[3] << 16);
    v.z = h[4] | (h[5] << 16);
    v.w = h[6] | (h[7] << 16);
    *(uint4*)(Pimg + (size_t)r * 256 + k0) = v;
}

// ---------------- segment sums as one-hot MFMA GEMM + fine positive dot -----
__global__ __launch_bounds__(256, 2) void k_seg(
        const float* __restrict__ feat, const float* __restrict__ p1,
        const int* __restrict__ l1, const int* __restrict__ l2,
        const int* __restrict__ l3, float* __restrict__ ws,
        int partMask, int useAtomic) {
    __shared__ int labs23[512];   // l2 | l3<<16
    __shared__ int labs1[512];
    __shared__ float psum[4];
    const int tid  = threadIdx.x;
    const int lane = tid & 63;
    const int wv   = tid >> 6;          // 0..3
    const int g    = lane >> 4;         // 0..3 (k-group)
    const int rs   = lane & 15;
    const int chunk = blockIdx.x >> 1, half = blockIdx.x & 1;
    const int base  = chunk * 512;
    const int dimbase = half * 128 + wv * 32;

    for (int j = tid; j < 512; j += 256) {
        labs23[j] = l2[base + j] | (l3[base + j] << 16);
        labs1[j]  = l1[base + j];
    }
    __syncthreads();

    f32x4 acc[9][2];
#pragma unroll
    for (int mt = 0; mt < 9; ++mt)
#pragma unroll
        for (int nt = 0; nt < 2; ++nt) acc[mt][nt] = (f32x4){0.f, 0.f, 0.f, 0.f};

    float fA[16], pA[16], fB[16], pB[16];
    float posacc = 0.f;

#define LOADSTEP(u, F, P) { \
    const int sl0 = (u) * 32 + 8 * g; \
    _Pragma("unroll") \
    for (int j = 0; j < 8; ++j) { \
        const int sl = sl0 + j; \
        const size_t fb = (size_t)(base + sl) * 256 + dimbase + rs; \
        F[j]     = feat[fb]; \
        F[8 + j] = feat[fb + 16]; \
        const size_t pb = (size_t)labs1[sl] * 256 + dimbase + rs; \
        P[j]     = p1[pb]; \
        P[8 + j] = p1[pb + 16]; \
    } }

#define PROCSTEP(u, F, P) { \
    _Pragma("unroll") \
    for (int j = 0; j < 16; ++j) posacc = fmaf(F[j], P[j], posacc); \
    union { unsigned w[4]; short8 s; } b0, b1; \
    _Pragma("unroll") \
    for (int q = 0; q < 4; ++q) { \
        asm("v_cvt_pk_bf16_f32 %0, %1, %2" : "=v"(b0.w[q]) : "v"(F[2*q]),   "v"(F[2*q+1])); \
        asm("v_cvt_pk_bf16_f32 %0, %1, %2" : "=v"(b1.w[q]) : "v"(F[8+2*q]), "v"(F[8+2*q+1])); \
    } \
    int d2[8], d3[8]; \
    { const int sl0 = (u) * 32 + 8 * g; \
      _Pragma("unroll") \
      for (int j = 0; j < 8; ++j) { \
          const int v = labs23[sl0 + j]; \
          d2[j] = (v & 0xffff) - rs; \
          d3[j] = (v >> 16) - rs; \
      } } \
    _Pragma("unroll") \
    for (int mt = 0; mt < 7; ++mt) { \
        union { unsigned w[4]; short8 s; } af; \
        _Pragma("unroll") \
        for (int q = 0; q < 4; ++q) { \
            unsigned w = (d2[2*q] == mt*16) ? 0x3F80u : 0u; \
            if (d2[2*q+1] == mt*16) w |= 0x3F800000u; \
            af.w[q] = w; \
        } \
        acc[mt][0] = __builtin_amdgcn_mfma_f32_16x16x32_bf16(af.s, b0.s, acc[mt][0], 0, 0, 0); \
        acc[mt][1] = __builtin_amdgcn_mfma_f32_16x16x32_bf16(af.s, b1.s, acc[mt][1], 0, 0, 0); \
    } \
    _Pragma("unroll") \
    for (int mt = 0; mt < 2; ++mt) { \
        union { unsigned w[4]; short8 s; } af; \
        _Pragma("unroll") \
        for (int q = 0; q < 4; ++q) { \
            unsigned w = (d3[2*q] == mt*16) ? 0x3F80u : 0u; \
            if (d3[2*q+1] == mt*16) w |= 0x3F800000u; \
            af.w[q] = w; \
        } \
        acc[7+mt][0] = __builtin_amdgcn_mfma_f32_16x16x32_bf16(af.s, b0.s, acc[7+mt][0], 0, 0, 0); \
        acc[7+mt][1] = __builtin_amdgcn_mfma_f32_16x16x32_bf16(af.s, b1.s, acc[7+mt][1], 0, 0, 0); \
    } }

    LOADSTEP(0, fA, pA);
#pragma unroll 1
    for (int t = 0; t < 16; t += 2) {
        LOADSTEP(t + 1, fB, pB);
        PROCSTEP(t, fA, pA);
        if (t + 2 < 16) LOADSTEP(t + 2, fA, pA);
        PROCSTEP(t + 1, fB, pB);
    }
#undef LOADSTEP
#undef PROCSTEP

    // ---- epilogue: write partials. row = mt*16 + 4*g + r, col = dim ----
    float* part = ws + WS_SEG +
        (size_t)(useAtomic ? (chunk & partMask) : chunk) * PART_FLOATS;
#pragma unroll
    for (int mt = 0; mt < 9; ++mt)
#pragma unroll
        for (int nt = 0; nt < 2; ++nt)
#pragma unroll
            for (int r = 0; r < 4; ++r) {
                float v = acc[mt][nt][r];
                float* dst = &part[(mt * 16 + 4 * g + r) * 256 + dimbase + nt * 16 + rs];
                if (useAtomic) atomicAdd(dst, v); else *dst = v;
            }

    // ---- per-class counts (half 0 only) ----
    if (half == 0 && tid < 120) {
        float cnt = 0.f;
        const int isl2 = tid < 100;
        const int cls = isl2 ? tid : tid - 100;
#pragma unroll 8
        for (int j = 0; j < 512; ++j) {
            int v = labs23[j];
            int lab = isl2 ? (v & 0xffff) : (v >> 16);
            cnt += (lab == cls) ? 1.f : 0.f;
        }
        float* dst = &part[NROWS * 256 + tid];
        if (useAtomic) atomicAdd(dst, cnt); else *dst = cnt;
    }

    // ---- reduce positive dot ----
#pragma unroll
    for (int m = 1; m < 64; m <<= 1) posacc += __shfl_xor(posacc, m);
    if (lane == 0) psum[wv] = posacc;
    __syncthreads();
    if (tid == 0) atomicAdd(&ws[WS_POS], psum[0] + psum[1] + psum[2] + psum[3]);
}

// ---------------- partials -> means (one block per class row) ----------------
__global__ __launch_bounds__(256, 4) void k_div(float* __restrict__ ws, int npart) {
    __shared__ float cred[4];
    const int c = blockIdx.x;             // 0..119
    const int d = threadIdx.x;            // dim
    const int prow = (c < 100) ? c : 112 + (c - 100);
    float cv = (d < npart) ? ws[WS_SEG + (size_t)d * PART_FLOATS + NROWS * 256 + c] : 0.f;
#pragma unroll
    for (int m = 1; m < 64; m <<= 1) cv += __shfl_xor(cv, m);
    if ((d & 63) == 0) cred[d >> 6] = cv;
    __syncthreads();
    const float cnt = cred[0] + cred[1] + cred[2] + cred[3];
    float a0=0,a1=0,a2=0,a3=0,a4=0,a5=0,a6=0,a7=0;
    int p = 0;
    for (; p + 8 <= npart; p += 8) {
        const float* b = ws + WS_SEG + (size_t)p * PART_FLOATS + prow * 256 + d;
        a0 += b[0 * (size_t)PART_FLOATS];
        a1 += b[1 * (size_t)PART_FLOATS];
        a2 += b[2 * (size_t)PART_FLOATS];
        a3 += b[3 * (size_t)PART_FLOATS];
        a4 += b[4 * (size_t)PART_FLOATS];
        a5 += b[5 * (size_t)PART_FLOATS];
        a6 += b[6 * (size_t)PART_FLOATS];
        a7 += b[7 * (size_t)PART_FLOATS];
    }
    for (; p < npart; ++p)
        a0 += ws[WS_SEG + (size_t)p * PART_FLOATS + prow * 256 + d];
    const float s = ((a0+a1)+(a2+a3)) + ((a4+a5)+(a6+a7));
    ws[256 + ((c < 100) ? c * 256 : 25600 + (c - 100) * 256) + d] = s / cnt;
}

// ---- opaque B loads (r4/r7-proven): asm is not rematerializable, so loads
// issue exactly once where written and outputs stay register-resident.
#define LOADB(dst, ptr, OFF) \
    asm volatile("global_load_dwordx4 %0, %1, off offset:" #OFF \
                 : "=v"(dst) : "v"(ptr))
#define LOADB8(buf, ptr) \
    LOADB(buf[0], ptr, 0);   LOADB(buf[1], ptr, 64);  \
    LOADB(buf[2], ptr, 128); LOADB(buf[3], ptr, 192); \
    LOADB(buf[4], ptr, 256); LOADB(buf[5], ptr, 320); \
    LOADB(buf[6], ptr, 384); LOADB(buf[7], ptr, 448)

// ---------------- fine level: MFMA GEMM + in-register biased sum-exp --------
// 256-ROW tile, retry of r8 with the spill fixed: __launch_bounds__(512,1)
// gives the allocator the full 512-VGPR budget (r8's (512,2) inexplicably
// allocated 128 and spilled 127 MB to scratch — the experiment never ran).
// Halves B (Pimg) re-read traffic 512->256 MB chip-wide, the one lever
// with a measured cost coefficient (r2: +512 MB <-> +56 us). 8 waves,
// Af = 128 KB LDS, 1 block/CU (2 waves/SIMD — proven sufficient r0-r6).
// Per-CU MFMA/LDS/A-traffic totals unchanged. Single B buffer; next-pass
// loads issued at end of each pass = 1-deep prefetch (WAR-safe in-order
// issue, validated r8: absmax 0 even under spill).
__global__ __launch_bounds__(512, 1) void k_fine(
        const float* __restrict__ feat, const unsigned short* __restrict__ Pimg,
        float* __restrict__ ws, int C1) {
    __shared__ __align__(16) unsigned short Af[256 * 256];  // 128 KB, swizzled
    __shared__ float Sbuf[256];
    __shared__ float redl[8];
    const int tid  = threadIdx.x;
    const int lane = tid & 63;
    const int wv   = tid >> 6;        // 0..7
    const int g    = lane >> 4;       // 0..3
    const int rs   = lane & 15;
    const int row0 = blockIdx.x * 256;

#define PBP(p) ((const char*)Pimg + (size_t)((p) * 256 + wv * 32 + rs) * 512 + g * 16)

    // ---- issue pass-0 B loads first: they complete under the staging ----
    short8 bA[2][8];
    { const char* pb = PBP(0); LOADB8(bA[0], pb); LOADB8(bA[1], pb + 8192); }

    // ---- stage A: 8 floats/unit -> cvt_pk x4 -> ds_write_b128, swizzled ----
#pragma unroll
    for (int i = 0; i < 16; ++i) {
        int u = tid + i * 512;                 // 16B unit, 8192 total
        int r = u >> 5, q8 = u & 31;
        const float* src = feat + (size_t)(row0 + r) * 256 + q8 * 8;
        f32x4 v0 = *(const f32x4*)(src);
        f32x4 v1 = *(const f32x4*)(src + 4);
        uint4 pk;
        asm("v_cvt_pk_bf16_f32 %0, %1, %2" : "=v"(pk.x) : "v"(v0[0]), "v"(v0[1]));
        asm("v_cvt_pk_bf16_f32 %0, %1, %2" : "=v"(pk.y) : "v"(v0[2]), "v"(v0[3]));
        asm("v_cvt_pk_bf16_f32 %0, %1, %2" : "=v"(pk.z) : "v"(v1[0]), "v"(v1[1]));
        asm("v_cvt_pk_bf16_f32 %0, %1, %2" : "=v"(pk.w) : "v"(v1[2]), "v"(v1[3]));
        *(uint4*)((char*)Af + r * 512 + ((q8 * 16) ^ ((r & 7) << 4))) = pk;
    }
    if (tid < 256) Sbuf[tid] = 0.f;
    __syncthreads();   // compiler drains vmcnt here -> bA valid after barrier

    float es[16][4];
#pragma unroll
    for (int a = 0; a < 16; ++a)
#pragma unroll
        for (int b = 0; b < 4; ++b) es[a][b] = 0.f;

#pragma unroll 1
    for (int p = 0; p < 4; ++p) {
        asm volatile("s_waitcnt vmcnt(0)" ::: "memory");   // bA complete
        __builtin_amdgcn_sched_barrier(0);
#pragma unroll
        for (int rt = 0; rt < 16; ++rt) {
            f32x4 acc0 = (f32x4){0.f, 0.f, 0.f, 0.f};
            f32x4 acc1 = (f32x4){0.f, 0.f, 0.f, 0.f};
            const int ar = rt * 16 + rs;
            const char* abase = (const char*)Af + ar * 512;
            const int sw = (ar & 7) << 4;
#pragma unroll
            for (int ks = 0; ks < 8; ++ks) {
                short8 a = *(const short8*)(abase + ((ks * 64 + g * 16) ^ sw));
                acc0 = __builtin_amdgcn_mfma_f32_16x16x32_bf16(a, bA[0][ks], acc0, 0, 0, 0);
                acc1 = __builtin_amdgcn_mfma_f32_16x16x32_bf16(a, bA[1][ks], acc1, 0, 0, 0);
            }
            // ---- in-register epilogue: paired exp, one s_nop per 2 ----
#pragma unroll
            for (int r = 0; r < 4; ++r) {
                float t0 = fmaf(acc0[r], SC2, -BIAS);
                float t1 = fmaf(acc1[r], SC2, -BIAS);
                float e0, e1;
                asm("v_exp_f32 %0, %2\n\t"
                    "v_exp_f32 %1, %3\n\t"
                    "s_nop 1"
                    : "=&v"(e0), "=&v"(e1) : "v"(t0), "v"(t1));
                es[rt][r] += e0 + e1;
            }
        }
        // issue next pass's B loads (in-order issue: MFMAs above already
        // read the old bA values; WAR is safe, anti-dep kept post-RA)
        if (p + 1 < 4) {
            const char* pb = PBP(p + 1);
            LOADB8(bA[0], pb); LOADB8(bA[1], pb + 8192);
        }
    }
#undef PBP

    // ---- one reduction pass: row = rt*16 + 4*g + r ----
#pragma unroll
    for (int rt = 0; rt < 16; ++rt) {
#pragma unroll
        for (int r = 0; r < 4; ++r) {
            float e = es[rt][r];
            e += __shfl_xor(e, 1);
            e += __shfl_xor(e, 2);
            e += __shfl_xor(e, 4);
            e += __shfl_xor(e, 8);
            if (rs == 0) atomicAdd(&Sbuf[rt * 16 + 4 * g + r], e);
        }
    }
    __syncthreads();
    // ---- lse over the 256 rows (first 4 waves) ----
    if (tid < 256) {
        float S = Sbuf[tid] - (float)(1024 - C1) * exp2f(-BIAS);  // exact pad removal
        float lse = (BIAS + log2f(S)) * 0.6931471805599453f;
#pragma unroll
        for (int m = 1; m < 64; m <<= 1) lse += __shfl_xor(lse, m);
        if (lane == 0) redl[tid >> 6] = lse;
    }
    __syncthreads();
    if (tid == 0)
        atomicAdd(&ws[WS_LSE], (redl[0] + redl[1]) + (redl[2] + redl[3]));
}

// ---------------- proto-NCE on the means ----------------
__global__ __launch_bounds__(128, 4) void k_nce(
        const float* __restrict__ p2, const float* __restrict__ p3,
        float* __restrict__ ws) {
    __shared__ __align__(16) float mrow[256];
    __shared__ float sim[128];
    __shared__ float red[2];
    const int b = blockIdx.x;
    const float* means; const float* prot; int C, r, accIdx;
    if (b < 100) { means = ws + WS_S2; prot = p2; C = 100; r = b;       accIdx = WS_ACC2; }
    else         { means = ws + WS_S3; prot = p3; C = 20;  r = b - 100; accIdx = WS_ACC3; }
    const int tid = threadIdx.x;
    const int lane = tid & 63;
    mrow[tid]       = means[(size_t)r * 256 + tid];
    mrow[128 + tid] = means[(size_t)r * 256 + 128 + tid];
    __syncthreads();
    if (tid < C) {
        const f32x4* mr = (const f32x4*)mrow;
        const f32x4* pr = (const f32x4*)(prot + (size_t)tid * 256);
        float acc = 0.f;
#pragma unroll 4
        for (int k = 0; k < 64; ++k) {
            f32x4 m = mr[k], qv = pr[k];
            acc += m[0]*qv[0] + m[1]*qv[1] + m[2]*qv[2] + m[3]*qv[3];
        }
        sim[tid] = acc * 10.0f;
    }
    __syncthreads();
    float v = (tid < C) ? sim[tid] : -1e30f;
#pragma unroll
    for (int m = 1; m < 64; m <<= 1) v = fmaxf(v, __shfl_xor(v, m));
    if (lane == 0) red[tid >> 6] = v;
    __syncthreads();
    const float mx = fmaxf(red[0], red[1]);
    float e = (tid < C) ? __expf(sim[tid] - mx) : 0.f;
#pragma unroll
    for (int m = 1; m < 64; m <<= 1) e += __shfl_xor(e, m);
    __syncthreads();
    if (lane == 0) red[tid >> 6] = e;
    __syncthreads();
    if (tid == 0) {
        float lse = mx + logf(red[0] + red[1]);
        atomicAdd(&ws[accIdx], lse - sim[r]);
    }
}

// ---------------- finalize ----------------
__global__ void k_final(const float* __restrict__ ws, float* __restrict__ out, float Nf) {
    if (threadIdx.x == 0 && blockIdx.x == 0) {
        float fine   = (ws[WS_LSE] - 10.0f * ws[WS_POS]) / Nf;
        float coarse = ws[WS_ACC2] / 100.0f;
        float con    = ws[WS_ACC3] / 20.0f;
        out[0] = 0.5f * fine + 0.5f * coarse + 0.0f * con;
        out[1] = fine;
        out[2] = coarse;
        out[3] = con;
    }
}

extern "C" void kernel_launch(void* const* d_in, const int* in_sizes, int n_in,
                              void* d_out, int out_size, void* d_ws, size_t ws_size,
                              hipStream_t stream) {
    const float* feat = (const float*)d_in[0];
    const float* p1   = (const float*)d_in[1];
    const int*   l1   = (const int*)d_in[2];
    const float* p2   = (const float*)d_in[3];
    const int*   l2   = (const int*)d_in[4];
    const float* p3   = (const float*)d_in[5];
    const int*   l3   = (const int*)d_in[6];
    float* out = (float*)d_out;
    float* ws  = (float*)d_ws;
    const int n  = in_sizes[0] / 256;       // 131072
    const int c1 = in_sizes[1] / 256;       // 1000
    unsigned short* Pimg = (unsigned short*)((char*)d_ws + PIMG_BYTE_OFF);

    // adaptive partial-buffer count (nchunk = n/512 = 256)
    const int nchunk = n / 512;
    long nfull = ((long)(ws_size / 4) - WS_SEG) / PART_FLOATS;
    int useAtomic, npart;
    if (nfull >= nchunk) { useAtomic = 0; npart = nchunk; }
    else {
        useAtomic = 1;
        npart = 1;
        while (npart * 2 <= (int)nfull && npart < 32) npart <<= 1;
    }

    if (useAtomic)
        k_zero <<<(npart * PART_FLOATS + 255) / 256, 256, 0, stream>>>(ws + WS_SEG, npart * PART_FLOATS);
    k_prep <<<128, 256, 0, stream>>>(p1, Pimg, ws, c1);
    k_seg  <<<nchunk * 2, 256, 0, stream>>>(feat, p1, l1, l2, l3, ws, npart - 1, useAtomic);
    k_div  <<<120, 256, 0, stream>>>(ws, npart);
    k_fine <<<n / 256, 512, 0, stream>>>(feat, Pimg, ws, c1);
    k_nce  <<<120, 128, 0, stream>>>(p2, p3, ws);
    k_final<<<1, 64, 0, stream>>>(ws, out, (float)n);
}

// Round 10
// 232.660 us; speedup vs baseline: 1.3939x; 1.3687x over previous
//
#include <hip/hip_runtime.h>
#include <math.h>

// ---------------- workspace layout ----------------
#define WS_POS   0
#define WS_LSE   1
#define WS_ACC2  2
#define WS_ACC3  3
#define WS_S2    256
#define WS_S3    (256+25600)
#define WS_SEG   163840
#define NROWS    144                 // 112 padded l2 rows + 32 padded l3 rows
#define PART_FLOATS (NROWS*256 + 128)  // 36992; counts at [36864, 36984)
#define PIMG_BYTE_OFF 131072

#define SC2  14.426950408889634f    // (1/TEMP=10) * log2(e)
#define BIAS 48.0f

typedef __attribute__((ext_vector_type(4))) float f32x4;
typedef __attribute__((ext_vector_type(8))) short short8;

static __device__ __forceinline__ unsigned f2bf(float f) {
    union { float f; unsigned u; } x; x.f = f;
    unsigned r = x.u + 0x7FFFu + ((x.u >> 16) & 1u);   // RNE
    return r >> 16;
}

// ---------------- generic zero ----------------
__global__ void k_zero(float* __restrict__ p, int count) {
    int i = blockIdx.x * 256 + threadIdx.x;
    if (i < count) p[i] = 0.f;
}

// ---------------- build plain bf16 proto image [1024][256], pad rows zero ----
// (also zeroes ws[0..256) from block 0 — saves a separate launch)
__global__ void k_prep(const float* __restrict__ p1, unsigned short* __restrict__ Pimg,
                       float* __restrict__ ws, int C1) {
    if (blockIdx.x == 0) ws[threadIdx.x] = 0.f;
    int e = blockIdx.x * 256 + threadIdx.x;   // 32768 threads, 8 elems each
    int r  = e >> 5;
    int k0 = (e & 31) * 8;
    unsigned h[8];
#pragma unroll
    for (int j = 0; j < 8; ++j)
        h[j] = (r < C1) ? f2bf(p1[(size_t)r * 256 + k0 + j]) : 0u;
    uint4 v;
    v.x = h[0] | (h[1] << 16);
    v.y = h[2] | (h[3] << 16);
    v.z = h[4] | (h[5] << 16);
    v.w = h[6] | (h[7] << 16);
    *(uint4*)(Pimg + (size_t)r * 256 + k0) = v;
}

// ---------------- segment sums as one-hot MFMA GEMM + fine positive dot -----
__global__ __launch_bounds__(256, 2) void k_seg(
        const float* __restrict__ feat, const float* __restrict__ p1,
        const int* __restrict__ l1, const int* __restrict__ l2,
        const int* __restrict__ l3, float* __restrict__ ws,
        int partMask, int useAtomic) {
    __shared__ int labs23[512];   // l2 | l3<<16
    __shared__ int labs1[512];
    __shared__ float psum[4];
    const int tid  = threadIdx.x;
    const int lane = tid & 63;
    const int wv   = tid >> 6;          // 0..3
    const int g    = lane >> 4;         // 0..3 (k-group)
    const int rs   = lane & 15;
    const int chunk = blockIdx.x >> 1, half = blockIdx.x & 1;
    const int base  = chunk * 512;
    const int dimbase = half * 128 + wv * 32;

    for (int j = tid; j < 512; j += 256) {
        labs23[j] = l2[base + j] | (l3[base + j] << 16);
        labs1[j]  = l1[base + j];
    }
    __syncthreads();

    f32x4 acc[9][2];
#pragma unroll
    for (int mt = 0; mt < 9; ++mt)
#pragma unroll
        for (int nt = 0; nt < 2; ++nt) acc[mt][nt] = (f32x4){0.f, 0.f, 0.f, 0.f};

    float fA[16], pA[16], fB[16], pB[16];
    float posacc = 0.f;

#define LOADSTEP(u, F, P) { \
    const int sl0 = (u) * 32 + 8 * g; \
    _Pragma("unroll") \
    for (int j = 0; j < 8; ++j) { \
        const int sl = sl0 + j; \
        const size_t fb = (size_t)(base + sl) * 256 + dimbase + rs; \
        F[j]     = feat[fb]; \
        F[8 + j] = feat[fb + 16]; \
        const size_t pb = (size_t)labs1[sl] * 256 + dimbase + rs; \
        P[j]     = p1[pb]; \
        P[8 + j] = p1[pb + 16]; \
    } }

#define PROCSTEP(u, F, P) { \
    _Pragma("unroll") \
    for (int j = 0; j < 16; ++j) posacc = fmaf(F[j], P[j], posacc); \
    union { unsigned w[4]; short8 s; } b0, b1; \
    _Pragma("unroll") \
    for (int q = 0; q < 4; ++q) { \
        asm("v_cvt_pk_bf16_f32 %0, %1, %2" : "=v"(b0.w[q]) : "v"(F[2*q]),   "v"(F[2*q+1])); \
        asm("v_cvt_pk_bf16_f32 %0, %1, %2" : "=v"(b1.w[q]) : "v"(F[8+2*q]), "v"(F[8+2*q+1])); \
    } \
    int d2[8], d3[8]; \
    { const int sl0 = (u) * 32 + 8 * g; \
      _Pragma("unroll") \
      for (int j = 0; j < 8; ++j) { \
          const int v = labs23[sl0 + j]; \
          d2[j] = (v & 0xffff) - rs; \
          d3[j] = (v >> 16) - rs; \
      } } \
    _Pragma("unroll") \
    for (int mt = 0; mt < 7; ++mt) { \
        union { unsigned w[4]; short8 s; } af; \
        _Pragma("unroll") \
        for (int q = 0; q < 4; ++q) { \
            unsigned w = (d2[2*q] == mt*16) ? 0x3F80u : 0u; \
            if (d2[2*q+1] == mt*16) w |= 0x3F800000u; \
            af.w[q] = w; \
        } \
        acc[mt][0] = __builtin_amdgcn_mfma_f32_16x16x32_bf16(af.s, b0.s, acc[mt][0], 0, 0, 0); \
        acc[mt][1] = __builtin_amdgcn_mfma_f32_16x16x32_bf16(af.s, b1.s, acc[mt][1], 0, 0, 0); \
    } \
    _Pragma("unroll") \
    for (int mt = 0; mt < 2; ++mt) { \
        union { unsigned w[4]; short8 s; } af; \
        _Pragma("unroll") \
        for (int q = 0; q < 4; ++q) { \
            unsigned w = (d3[2*q] == mt*16) ? 0x3F80u : 0u; \
            if (d3[2*q+1] == mt*16) w |= 0x3F800000u; \
            af.w[q] = w; \
        } \
        acc[7+mt][0] = __builtin_amdgcn_mfma_f32_16x16x32_bf16(af.s, b0.s, acc[7+mt][0], 0, 0, 0); \
        acc[7+mt][1] = __builtin_amdgcn_mfma_f32_16x16x32_bf16(af.s, b1.s, acc[7+mt][1], 0, 0, 0); \
    } }

    LOADSTEP(0, fA, pA);
#pragma unroll 1
    for (int t = 0; t < 16; t += 2) {
        LOADSTEP(t + 1, fB, pB);
        PROCSTEP(t, fA, pA);
        if (t + 2 < 16) LOADSTEP(t + 2, fA, pA);
        PROCSTEP(t + 1, fB, pB);
    }
#undef LOADSTEP
#undef PROCSTEP

    // ---- epilogue: write partials. row = mt*16 + 4*g + r, col = dim ----
    float* part = ws + WS_SEG +
        (size_t)(useAtomic ? (chunk & partMask) : chunk) * PART_FLOATS;
#pragma unroll
    for (int mt = 0; mt < 9; ++mt)
#pragma unroll
        for (int nt = 0; nt < 2; ++nt)
#pragma unroll
            for (int r = 0; r < 4; ++r) {
                float v = acc[mt][nt][r];
                float* dst = &part[(mt * 16 + 4 * g + r) * 256 + dimbase + nt * 16 + rs];
                if (useAtomic) atomicAdd(dst, v); else *dst = v;
            }

    // ---- per-class counts (half 0 only) ----
    if (half == 0 && tid < 120) {
        float cnt = 0.f;
        const int isl2 = tid < 100;
        const int cls = isl2 ? tid : tid - 100;
#pragma unroll 8
        for (int j = 0; j < 512; ++j) {
            int v = labs23[j];
            int lab = isl2 ? (v & 0xffff) : (v >> 16);
            cnt += (lab == cls) ? 1.f : 0.f;
        }
        float* dst = &part[NROWS * 256 + tid];
        if (useAtomic) atomicAdd(dst, cnt); else *dst = cnt;
    }

    // ---- reduce positive dot ----
#pragma unroll
    for (int m = 1; m < 64; m <<= 1) posacc += __shfl_xor(posacc, m);
    if (lane == 0) psum[wv] = posacc;
    __syncthreads();
    if (tid == 0) atomicAdd(&ws[WS_POS], psum[0] + psum[1] + psum[2] + psum[3]);
}

// ---------------- partials -> means (one block per class row) ----------------
__global__ __launch_bounds__(256, 4) void k_div(float* __restrict__ ws, int npart) {
    __shared__ float cred[4];
    const int c = blockIdx.x;             // 0..119
    const int d = threadIdx.x;            // dim
    const int prow = (c < 100) ? c : 112 + (c - 100);
    float cv = (d < npart) ? ws[WS_SEG + (size_t)d * PART_FLOATS + NROWS * 256 + c] : 0.f;
#pragma unroll
    for (int m = 1; m < 64; m <<= 1) cv += __shfl_xor(cv, m);
    if ((d & 63) == 0) cred[d >> 6] = cv;
    __syncthreads();
    const float cnt = cred[0] + cred[1] + cred[2] + cred[3];
    float a0=0,a1=0,a2=0,a3=0,a4=0,a5=0,a6=0,a7=0;
    int p = 0;
    for (; p + 8 <= npart; p += 8) {
        const float* b = ws + WS_SEG + (size_t)p * PART_FLOATS + prow * 256 + d;
        a0 += b[0 * (size_t)PART_FLOATS];
        a1 += b[1 * (size_t)PART_FLOATS];
        a2 += b[2 * (size_t)PART_FLOATS];
        a3 += b[3 * (size_t)PART_FLOATS];
        a4 += b[4 * (size_t)PART_FLOATS];
        a5 += b[5 * (size_t)PART_FLOATS];
        a6 += b[6 * (size_t)PART_FLOATS];
        a7 += b[7 * (size_t)PART_FLOATS];
    }
    for (; p < npart; ++p)
        a0 += ws[WS_SEG + (size_t)p * PART_FLOATS + prow * 256 + d];
    const float s = ((a0+a1)+(a2+a3)) + ((a4+a5)+(a6+a7));
    ws[256 + ((c < 100) ? c * 256 : 25600 + (c - 100) * 256) + d] = s / cnt;
}

// ---- opaque B loads (r4/r7-proven): asm is not rematerializable, so loads
// issue exactly once where written and outputs stay register-resident.
#define LOADB(dst, ptr, OFF) \
    asm volatile("global_load_dwordx4 %0, %1, off offset:" #OFF \
                 : "=v"(dst) : "v"(ptr))
#define LOADB8(buf, ptr) \
    LOADB(buf[0], ptr, 0);   LOADB(buf[1], ptr, 64);  \
    LOADB(buf[2], ptr, 128); LOADB(buf[3], ptr, 192); \
    LOADB(buf[4], ptr, 256); LOADB(buf[5], ptr, 320); \
    LOADB(buf[6], ptr, 384); LOADB(buf[7], ptr, 448)

// ---------------- fine level: MFMA GEMM + in-register biased sum-exp --------
// 256-ROW tile, third attempt, register demand CUT to fit the allocator's
// empirical 128-VGPR cap for 512-thread kernels (r5/r8/r9: it never grants
// more, whatever launch_bounds says). The 64-reg cross-pass es[16][4] is
// eliminated: the shfl-reduce + Sbuf accumulation now runs PER PASS (LDS
// atomicAdd), so live set = bA 64 + acc 8 + temps/addr ~ 115 < 128.
// The per-pass reduce also covers the end-of-pass B-load issue latency.
// B (Pimg) traffic halves 512 -> 256 MB chip-wide (r2-measured lever:
// +512 MB <-> +56 us). 8 waves, Af = 128 KB, 1 block/CU, 2 waves/SIMD.
// Gate: WRITE_SIZE must stay ~32 KB (no scratch) — r8/r9's failure mode.
__global__ __launch_bounds__(512, 2) void k_fine(
        const float* __restrict__ feat, const unsigned short* __restrict__ Pimg,
        float* __restrict__ ws, int C1) {
    __shared__ __align__(16) unsigned short Af[256 * 256];  // 128 KB, swizzled
    __shared__ float Sbuf[256];
    __shared__ float redl[8];
    const int tid  = threadIdx.x;
    const int lane = tid & 63;
    const int wv   = tid >> 6;        // 0..7
    const int g    = lane >> 4;       // 0..3
    const int rs   = lane & 15;
    const int row0 = blockIdx.x * 256;

#define PBP(p) ((const char*)Pimg + (size_t)((p) * 256 + wv * 32 + rs) * 512 + g * 16)

    // ---- issue pass-0 B loads first: they complete under the staging ----
    short8 bA[2][8];
    { const char* pb = PBP(0); LOADB8(bA[0], pb); LOADB8(bA[1], pb + 8192); }

    // ---- stage A: 8 floats/unit -> cvt_pk x4 -> ds_write_b128, swizzled ----
#pragma unroll
    for (int i = 0; i < 16; ++i) {
        int u = tid + i * 512;                 // 16B unit, 8192 total
        int r = u >> 5, q8 = u & 31;
        const float* src = feat + (size_t)(row0 + r) * 256 + q8 * 8;
        f32x4 v0 = *(const f32x4*)(src);
        f32x4 v1 = *(const f32x4*)(src + 4);
        uint4 pk;
        asm("v_cvt_pk_bf16_f32 %0, %1, %2" : "=v"(pk.x) : "v"(v0[0]), "v"(v0[1]));
        asm("v_cvt_pk_bf16_f32 %0, %1, %2" : "=v"(pk.y) : "v"(v0[2]), "v"(v0[3]));
        asm("v_cvt_pk_bf16_f32 %0, %1, %2" : "=v"(pk.z) : "v"(v1[0]), "v"(v1[1]));
        asm("v_cvt_pk_bf16_f32 %0, %1, %2" : "=v"(pk.w) : "v"(v1[2]), "v"(v1[3]));
        *(uint4*)((char*)Af + r * 512 + ((q8 * 16) ^ ((r & 7) << 4))) = pk;
    }
    if (tid < 256) Sbuf[tid] = 0.f;
    __syncthreads();   // compiler drains vmcnt here -> bA valid after barrier

#pragma unroll 1
    for (int p = 0; p < 4; ++p) {
        asm volatile("s_waitcnt vmcnt(0)" ::: "memory");   // bA complete
        __builtin_amdgcn_sched_barrier(0);
#pragma unroll 1
        for (int rt = 0; rt < 16; ++rt) {
            f32x4 acc0 = (f32x4){0.f, 0.f, 0.f, 0.f};
            f32x4 acc1 = (f32x4){0.f, 0.f, 0.f, 0.f};
            const int ar = rt * 16 + rs;
            const char* abase = (const char*)Af + ar * 512;
            const int sw = (ar & 7) << 4;
#pragma unroll
            for (int ks = 0; ks < 8; ++ks) {
                short8 a = *(const short8*)(abase + ((ks * 64 + g * 16) ^ sw));
                acc0 = __builtin_amdgcn_mfma_f32_16x16x32_bf16(a, bA[0][ks], acc0, 0, 0, 0);
                acc1 = __builtin_amdgcn_mfma_f32_16x16x32_bf16(a, bA[1][ks], acc1, 0, 0, 0);
            }
            // ---- epilogue: paired exp, immediate per-pass reduce+flush ----
#pragma unroll
            for (int r = 0; r < 4; ++r) {
                float t0 = fmaf(acc0[r], SC2, -BIAS);
                float t1 = fmaf(acc1[r], SC2, -BIAS);
                float e0, e1;
                asm("v_exp_f32 %0, %2\n\t"
                    "v_exp_f32 %1, %3\n\t"
                    "s_nop 1"
                    : "=&v"(e0), "=&v"(e1) : "v"(t0), "v"(t1));
                float e = e0 + e1;
                e += __shfl_xor(e, 1);
                e += __shfl_xor(e, 2);
                e += __shfl_xor(e, 4);
                e += __shfl_xor(e, 8);
                if (rs == 0) atomicAdd(&Sbuf[rt * 16 + 4 * g + r], e);
            }
        }
        // issue next pass's B loads (in-order issue: all MFMAs above already
        // read the old bA values; WAR-safe — validated r8/r9, absmax 0)
        if (p + 1 < 4) {
            const char* pb = PBP(p + 1);
            LOADB8(bA[0], pb); LOADB8(bA[1], pb + 8192);
        }
    }
#undef PBP

    __syncthreads();
    // ---- lse over the 256 rows (first 4 waves) ----
    if (tid < 256) {
        float S = Sbuf[tid] - (float)(1024 - C1) * exp2f(-BIAS);  // exact pad removal
        float lse = (BIAS + log2f(S)) * 0.6931471805599453f;
#pragma unroll
        for (int m = 1; m < 64; m <<= 1) lse += __shfl_xor(lse, m);
        if (lane == 0) redl[tid >> 6] = lse;
    }
    __syncthreads();
    if (tid == 0)
        atomicAdd(&ws[WS_LSE], (redl[0] + redl[1]) + (redl[2] + redl[3]));
}

// ---------------- proto-NCE on the means ----------------
__global__ __launch_bounds__(128, 4) void k_nce(
        const float* __restrict__ p2, const float* __restrict__ p3,
        float* __restrict__ ws) {
    __shared__ __align__(16) float mrow[256];
    __shared__ float sim[128];
    __shared__ float red[2];
    const int b = blockIdx.x;
    const float* means; const float* prot; int C, r, accIdx;
    if (b < 100) { means = ws + WS_S2; prot = p2; C = 100; r = b;       accIdx = WS_ACC2; }
    else         { means = ws + WS_S3; prot = p3; C = 20;  r = b - 100; accIdx = WS_ACC3; }
    const int tid = threadIdx.x;
    const int lane = tid & 63;
    mrow[tid]       = means[(size_t)r * 256 + tid];
    mrow[128 + tid] = means[(size_t)r * 256 + 128 + tid];
    __syncthreads();
    if (tid < C) {
        const f32x4* mr = (const f32x4*)mrow;
        const f32x4* pr = (const f32x4*)(prot + (size_t)tid * 256);
        float acc = 0.f;
#pragma unroll 4
        for (int k = 0; k < 64; ++k) {
            f32x4 m = mr[k], qv = pr[k];
            acc += m[0]*qv[0] + m[1]*qv[1] + m[2]*qv[2] + m[3]*qv[3];
        }
        sim[tid] = acc * 10.0f;
    }
    __syncthreads();
    float v = (tid < C) ? sim[tid] : -1e30f;
#pragma unroll
    for (int m = 1; m < 64; m <<= 1) v = fmaxf(v, __shfl_xor(v, m));
    if (lane == 0) red[tid >> 6] = v;
    __syncthreads();
    const float mx = fmaxf(red[0], red[1]);
    float e = (tid < C) ? __expf(sim[tid] - mx) : 0.f;
#pragma unroll
    for (int m = 1; m < 64; m <<= 1) e += __shfl_xor(e, m);
    __syncthreads();
    if (lane == 0) red[tid >> 6] = e;
    __syncthreads();
    if (tid == 0) {
        float lse = mx + logf(red[0] + red[1]);
        atomicAdd(&ws[accIdx], lse - sim[r]);
    }
}

// ---------------- finalize ----------------
__global__ void k_final(const float* __restrict__ ws, float* __restrict__ out, float Nf) {
    if (threadIdx.x == 0 && blockIdx.x == 0) {
        float fine   = (ws[WS_LSE] - 10.0f * ws[WS_POS]) / Nf;
        float coarse = ws[WS_ACC2] / 100.0f;
        float con    = ws[WS_ACC3] / 20.0f;
        out[0] = 0.5f * fine + 0.5f * coarse + 0.0f * con;
        out[1] = fine;
        out[2] = coarse;
        out[3] = con;
    }
}

extern "C" void kernel_launch(void* const* d_in, const int* in_sizes, int n_in,
                              void* d_out, int out_size, void* d_ws, size_t ws_size,
                              hipStream_t stream) {
    const float* feat = (const float*)d_in[0];
    const float* p1   = (const float*)d_in[1];
    const int*   l1   = (const int*)d_in[2];
    const float* p2   = (const float*)d_in[3];
    const int*   l2   = (const int*)d_in[4];
    const float* p3   = (const float*)d_in[5];
    const int*   l3   = (const int*)d_in[6];
    float* out = (float*)d_out;
    float* ws  = (float*)d_ws;
    const int n  = in_sizes[0] / 256;       // 131072
    const int c1 = in_sizes[1] / 256;       // 1000
    unsigned short* Pimg = (unsigned short*)((char*)d_ws + PIMG_BYTE_OFF);

    // adaptive partial-buffer count (nchunk = n/512 = 256)
    const int nchunk = n / 512;
    long nfull = ((long)(ws_size / 4) - WS_SEG) / PART_FLOATS;
    int useAtomic, npart;
    if (nfull >= nchunk) { useAtomic = 0; npart = nchunk; }
    else {
        useAtomic = 1;
        npart = 1;
        while (npart * 2 <= (int)nfull && npart < 32) npart <<= 1;
    }

    if (useAtomic)
        k_zero <<<(npart * PART_FLOATS + 255) / 256, 256, 0, stream>>>(ws + WS_SEG, npart * PART_FLOATS);
    k_prep <<<128, 256, 0, stream>>>(p1, Pimg, ws, c1);
    k_seg  <<<nchunk * 2, 256, 0, stream>>>(feat, p1, l1, l2, l3, ws, npart - 1, useAtomic);
    k_div  <<<120, 256, 0, stream>>>(ws, npart);
    k_fine <<<n / 256, 512, 0, stream>>>(feat, Pimg, ws, c1);
    k_nce  <<<120, 128, 0, stream>>>(p2, p3, ws);
    k_final<<<1, 64, 0, stream>>>(ws, out, (float)n);
}

// Round 11
// 161.445 us; speedup vs baseline: 2.0088x; 1.4411x over previous
//
#include <hip/hip_runtime.h>
#include <math.h>

// ---------------- workspace layout ----------------
#define WS_POS   0
#define WS_LSE   1
#define WS_ACC2  2
#define WS_ACC3  3
#define WS_S2    256
#define WS_S3    (256+25600)
#define WS_SEG   163840
#define NROWS    144                 // 112 padded l2 rows + 32 padded l3 rows
#define PART_FLOATS (NROWS*256 + 128)  // 36992; counts at [36864, 36984)
#define PIMG_BYTE_OFF 131072

#define SC2  14.426950408889634f    // (1/TEMP=10) * log2(e)
#define BIAS 48.0f

typedef __attribute__((ext_vector_type(4))) float f32x4;
typedef __attribute__((ext_vector_type(8))) short short8;

static __device__ __forceinline__ unsigned f2bf(float f) {
    union { float f; unsigned u; } x; x.f = f;
    unsigned r = x.u + 0x7FFFu + ((x.u >> 16) & 1u);   // RNE
    return r >> 16;
}

// ---------------- generic zero ----------------
__global__ void k_zero(float* __restrict__ p, int count) {
    int i = blockIdx.x * 256 + threadIdx.x;
    if (i < count) p[i] = 0.f;
}

// ---------------- build plain bf16 proto image [1024][256], pad rows zero ----
// (also zeroes ws[0..256) from block 0 — saves a separate launch)
__global__ void k_prep(const float* __restrict__ p1, unsigned short* __restrict__ Pimg,
                       float* __restrict__ ws, int C1) {
    if (blockIdx.x == 0) ws[threadIdx.x] = 0.f;
    int e = blockIdx.x * 256 + threadIdx.x;   // 32768 threads, 8 elems each
    int r  = e >> 5;
    int k0 = (e & 31) * 8;
    unsigned h[8];
#pragma unroll
    for (int j = 0; j < 8; ++j)
        h[j] = (r < C1) ? f2bf(p1[(size_t)r * 256 + k0 + j]) : 0u;
    uint4 v;
    v.x = h[0] | (h[1] << 16);
    v.y = h[2] | (h[3] << 16);
    v.z = h[4] | (h[5] << 16);
    v.w = h[6] | (h[7] << 16);
    *(uint4*)(Pimg + (size_t)r * 256 + k0) = v;
}

// ---------------- segment sums as one-hot MFMA GEMM + fine positive dot -----
__global__ __launch_bounds__(256, 2) void k_seg(
        const float* __restrict__ feat, const float* __restrict__ p1,
        const int* __restrict__ l1, const int* __restrict__ l2,
        const int* __restrict__ l3, float* __restrict__ ws,
        int partMask, int useAtomic) {
    __shared__ int labs23[512];   // l2 | l3<<16
    __shared__ int labs1[512];
    __shared__ float psum[4];
    const int tid  = threadIdx.x;
    const int lane = tid & 63;
    const int wv   = tid >> 6;          // 0..3
    const int g    = lane >> 4;         // 0..3 (k-group)
    const int rs   = lane & 15;
    const int chunk = blockIdx.x >> 1, half = blockIdx.x & 1;
    const int base  = chunk * 512;
    const int dimbase = half * 128 + wv * 32;

    for (int j = tid; j < 512; j += 256) {
        labs23[j] = l2[base + j] | (l3[base + j] << 16);
        labs1[j]  = l1[base + j];
    }
    __syncthreads();

    f32x4 acc[9][2];
#pragma unroll
    for (int mt = 0; mt < 9; ++mt)
#pragma unroll
        for (int nt = 0; nt < 2; ++nt) acc[mt][nt] = (f32x4){0.f, 0.f, 0.f, 0.f};

    float fA[16], pA[16], fB[16], pB[16];
    float posacc = 0.f;

#define LOADSTEP(u, F, P) { \
    const int sl0 = (u) * 32 + 8 * g; \
    _Pragma("unroll") \
    for (int j = 0; j < 8; ++j) { \
        const int sl = sl0 + j; \
        const size_t fb = (size_t)(base + sl) * 256 + dimbase + rs; \
        F[j]     = feat[fb]; \
        F[8 + j] = feat[fb + 16]; \
        const size_t pb = (size_t)labs1[sl] * 256 + dimbase + rs; \
        P[j]     = p1[pb]; \
        P[8 + j] = p1[pb + 16]; \
    } }

#define PROCSTEP(u, F, P) { \
    _Pragma("unroll") \
    for (int j = 0; j < 16; ++j) posacc = fmaf(F[j], P[j], posacc); \
    union { unsigned w[4]; short8 s; } b0, b1; \
    _Pragma("unroll") \
    for (int q = 0; q < 4; ++q) { \
        asm("v_cvt_pk_bf16_f32 %0, %1, %2" : "=v"(b0.w[q]) : "v"(F[2*q]),   "v"(F[2*q+1])); \
        asm("v_cvt_pk_bf16_f32 %0, %1, %2" : "=v"(b1.w[q]) : "v"(F[8+2*q]), "v"(F[8+2*q+1])); \
    } \
    int d2[8], d3[8]; \
    { const int sl0 = (u) * 32 + 8 * g; \
      _Pragma("unroll") \
      for (int j = 0; j < 8; ++j) { \
          const int v = labs23[sl0 + j]; \
          d2[j] = (v & 0xffff) - rs; \
          d3[j] = (v >> 16) - rs; \
      } } \
    _Pragma("unroll") \
    for (int mt = 0; mt < 7; ++mt) { \
        union { unsigned w[4]; short8 s; } af; \
        _Pragma("unroll") \
        for (int q = 0; q < 4; ++q) { \
            unsigned w = (d2[2*q] == mt*16) ? 0x3F80u : 0u; \
            if (d2[2*q+1] == mt*16) w |= 0x3F800000u; \
            af.w[q] = w; \
        } \
        acc[mt][0] = __builtin_amdgcn_mfma_f32_16x16x32_bf16(af.s, b0.s, acc[mt][0], 0, 0, 0); \
        acc[mt][1] = __builtin_amdgcn_mfma_f32_16x16x32_bf16(af.s, b1.s, acc[mt][1], 0, 0, 0); \
    } \
    _Pragma("unroll") \
    for (int mt = 0; mt < 2; ++mt) { \
        union { unsigned w[4]; short8 s; } af; \
        _Pragma("unroll") \
        for (int q = 0; q < 4; ++q) { \
            unsigned w = (d3[2*q] == mt*16) ? 0x3F80u : 0u; \
            if (d3[2*q+1] == mt*16) w |= 0x3F800000u; \
            af.w[q] = w; \
        } \
        acc[7+mt][0] = __builtin_amdgcn_mfma_f32_16x16x32_bf16(af.s, b0.s, acc[7+mt][0], 0, 0, 0); \
        acc[7+mt][1] = __builtin_amdgcn_mfma_f32_16x16x32_bf16(af.s, b1.s, acc[7+mt][1], 0, 0, 0); \
    } }

    LOADSTEP(0, fA, pA);
#pragma unroll 1
    for (int t = 0; t < 16; t += 2) {
        LOADSTEP(t + 1, fB, pB);
        PROCSTEP(t, fA, pA);
        if (t + 2 < 16) LOADSTEP(t + 2, fA, pA);
        PROCSTEP(t + 1, fB, pB);
    }
#undef LOADSTEP
#undef PROCSTEP

    // ---- epilogue: write partials. row = mt*16 + 4*g + r, col = dim ----
    float* part = ws + WS_SEG +
        (size_t)(useAtomic ? (chunk & partMask) : chunk) * PART_FLOATS;
#pragma unroll
    for (int mt = 0; mt < 9; ++mt)
#pragma unroll
        for (int nt = 0; nt < 2; ++nt)
#pragma unroll
            for (int r = 0; r < 4; ++r) {
                float v = acc[mt][nt][r];
                float* dst = &part[(mt * 16 + 4 * g + r) * 256 + dimbase + nt * 16 + rs];
                if (useAtomic) atomicAdd(dst, v); else *dst = v;
            }

    // ---- per-class counts (half 0 only) ----
    if (half == 0 && tid < 120) {
        float cnt = 0.f;
        const int isl2 = tid < 100;
        const int cls = isl2 ? tid : tid - 100;
#pragma unroll 8
        for (int j = 0; j < 512; ++j) {
            int v = labs23[j];
            int lab = isl2 ? (v & 0xffff) : (v >> 16);
            cnt += (lab == cls) ? 1.f : 0.f;
        }
        float* dst = &part[NROWS * 256 + tid];
        if (useAtomic) atomicAdd(dst, cnt); else *dst = cnt;
    }

    // ---- reduce positive dot ----
#pragma unroll
    for (int m = 1; m < 64; m <<= 1) posacc += __shfl_xor(posacc, m);
    if (lane == 0) psum[wv] = posacc;
    __syncthreads();
    if (tid == 0) atomicAdd(&ws[WS_POS], psum[0] + psum[1] + psum[2] + psum[3]);
}

// ---------------- partials -> means (one block per class row) ----------------
__global__ __launch_bounds__(256, 4) void k_div(float* __restrict__ ws, int npart) {
    __shared__ float cred[4];
    const int c = blockIdx.x;             // 0..119
    const int d = threadIdx.x;            // dim
    const int prow = (c < 100) ? c : 112 + (c - 100);
    float cv = (d < npart) ? ws[WS_SEG + (size_t)d * PART_FLOATS + NROWS * 256 + c] : 0.f;
#pragma unroll
    for (int m = 1; m < 64; m <<= 1) cv += __shfl_xor(cv, m);
    if ((d & 63) == 0) cred[d >> 6] = cv;
    __syncthreads();
    const float cnt = cred[0] + cred[1] + cred[2] + cred[3];
    float a0=0,a1=0,a2=0,a3=0,a4=0,a5=0,a6=0,a7=0;
    int p = 0;
    for (; p + 8 <= npart; p += 8) {
        const float* b = ws + WS_SEG + (size_t)p * PART_FLOATS + prow * 256 + d;
        a0 += b[0 * (size_t)PART_FLOATS];
        a1 += b[1 * (size_t)PART_FLOATS];
        a2 += b[2 * (size_t)PART_FLOATS];
        a3 += b[3 * (size_t)PART_FLOATS];
        a4 += b[4 * (size_t)PART_FLOATS];
        a5 += b[5 * (size_t)PART_FLOATS];
        a6 += b[6 * (size_t)PART_FLOATS];
        a7 += b[7 * (size_t)PART_FLOATS];
    }
    for (; p < npart; ++p)
        a0 += ws[WS_SEG + (size_t)p * PART_FLOATS + prow * 256 + d];
    const float s = ((a0+a1)+(a2+a3)) + ((a4+a5)+(a6+a7));
    ws[256 + ((c < 100) ? c * 256 : 25600 + (c - 100) * 256) + d] = s / cnt;
}

// ---- opaque B loads (r4-proven): asm is not rematerializable, so loads
// issue exactly once where written and outputs stay register-resident.
#define LOADB(dst, ptr, OFF) \
    asm volatile("global_load_dwordx4 %0, %1, off offset:" #OFF \
                 : "=v"(dst) : "v"(ptr))
#define LOADB8(buf, ptr) \
    LOADB(buf[0], ptr, 0);   LOADB(buf[1], ptr, 64);  \
    LOADB(buf[2], ptr, 128); LOADB(buf[3], ptr, 192); \
    LOADB(buf[4], ptr, 256); LOADB(buf[5], ptr, 320); \
    LOADB(buf[6], ptr, 384); LOADB(buf[7], ptr, 448)

// ---------------- fine level: MFMA GEMM + in-register biased sum-exp --------
// BEST MEASURED CONFIGURATION (r7: k_fine 98.4 us, total 161.6 us) —
// restored verbatim after r8/r9/r10 established:
//  - 256-row tiles with clean codegen REGRESS (r10: 170 us; B-traffic
//    lever refuted below 512 MB);
//  - 512-thread kernels are VGPR-capped at <=128 by the allocator
//    regardless of launch_bounds (r5/r8/r9: spills of 127 MB);
//  - LDS-halving (r4), TLP (r2 adj.), nt-loads (r6) all null.
// Structure: r0 geometry (128 rows, 64 KB Af, 4 waves, 2 blk/CU) +
// 2-deep cross-pass B prefetch with counted vmcnt(16) (the only measured
// positive lever, +2%). Every pipe <30% busy: stall-dominated floor of
// this structure family; the escape (8-phase schedule) needs >=256 VGPR
// at 512 thr, which this toolchain refuses.
__global__ __launch_bounds__(256, 2) void k_fine(
        const float* __restrict__ feat, const unsigned short* __restrict__ Pimg,
        float* __restrict__ ws, int C1) {
    __shared__ __align__(16) unsigned short Af[128 * 256];  // 64 KB, swizzled
    __shared__ float Sbuf[128];
    __shared__ float redl[2];
    const int tid  = threadIdx.x;
    const int lane = tid & 63;
    const int wv   = tid >> 6;        // 0..3
    const int g    = lane >> 4;       // 0..3
    const int rs   = lane & 15;
    const int row0 = blockIdx.x * 128;

#define PBP(p) ((const char*)Pimg + (size_t)((p) * 128 + wv * 32 + rs) * 512 + g * 16)

    // ---- issue pass-0 B loads first: they complete under the staging ----
    short8 bA[2][8], bB[2][8];
    { const char* pb = PBP(0); LOADB8(bA[0], pb); LOADB8(bA[1], pb + 8192); }

    // ---- stage A: 8 floats/unit -> cvt_pk x4 -> ds_write_b128, swizzled ----
#pragma unroll
    for (int i = 0; i < 16; ++i) {
        int u = tid + i * 256;                 // 16B unit, 4096 total
        int r = u >> 5, q8 = u & 31;
        const float* src = feat + (size_t)(row0 + r) * 256 + q8 * 8;
        f32x4 v0 = *(const f32x4*)(src);
        f32x4 v1 = *(const f32x4*)(src + 4);
        uint4 pk;
        asm("v_cvt_pk_bf16_f32 %0, %1, %2" : "=v"(pk.x) : "v"(v0[0]), "v"(v0[1]));
        asm("v_cvt_pk_bf16_f32 %0, %1, %2" : "=v"(pk.y) : "v"(v0[2]), "v"(v0[3]));
        asm("v_cvt_pk_bf16_f32 %0, %1, %2" : "=v"(pk.z) : "v"(v1[0]), "v"(v1[1]));
        asm("v_cvt_pk_bf16_f32 %0, %1, %2" : "=v"(pk.w) : "v"(v1[2]), "v"(v1[3]));
        *(uint4*)((char*)Af + r * 512 + ((q8 * 16) ^ ((r & 7) << 4))) = pk;
    }
    if (tid < 128) Sbuf[tid] = 0.f;
    __syncthreads();   // compiler drains vmcnt here -> bA valid after barrier

    float es[8][4];
#pragma unroll
    for (int a = 0; a < 8; ++a)
#pragma unroll
        for (int b = 0; b < 4; ++b) es[a][b] = 0.f;

#define PASS(BUF, pp) { \
    _Pragma("unroll") \
    for (int rt = 0; rt < 8; ++rt) { \
        f32x4 acc0 = (f32x4){0.f, 0.f, 0.f, 0.f}; \
        f32x4 acc1 = (f32x4){0.f, 0.f, 0.f, 0.f}; \
        const int ar = rt * 16 + rs; \
        const char* abase = (const char*)Af + ar * 512; \
        const int sw = (ar & 7) << 4; \
        _Pragma("unroll") \
        for (int ks = 0; ks < 8; ++ks) { \
            short8 a = *(const short8*)(abase + ((ks * 64 + g * 16) ^ sw)); \
            acc0 = __builtin_amdgcn_mfma_f32_16x16x32_bf16(a, BUF[0][ks], acc0, 0, 0, 0); \
            acc1 = __builtin_amdgcn_mfma_f32_16x16x32_bf16(a, BUF[1][ks], acc1, 0, 0, 0); \
        } \
        _Pragma("unroll") \
        for (int r = 0; r < 4; ++r) { \
            float t0 = fmaf(acc0[r], SC2, -BIAS); \
            float t1 = fmaf(acc1[r], SC2, -BIAS); \
            float e0, e1; \
            asm("v_exp_f32 %0, %2\n\t" \
                "v_exp_f32 %1, %3\n\t" \
                "s_nop 1" \
                : "=&v"(e0), "=&v"(e1) : "v"(t0), "v"(t1)); \
            es[rt][r] += e0 + e1; \
        } \
    } }

#pragma unroll 1
    for (int p = 0; p < 8; p += 2) {
        // prefetch pass p+1 into bB, then compute pass p from bA
        { const char* pb = PBP(p + 1); LOADB8(bB[0], pb); LOADB8(bB[1], pb + 8192); }
        asm volatile("s_waitcnt vmcnt(16)" ::: "memory");   // bA complete
        __builtin_amdgcn_sched_barrier(0);
        PASS(bA, p);
        // prefetch pass p+2 into bA (if any), then compute pass p+1 from bB
        if (p + 2 < 8) {
            const char* pb = PBP(p + 2); LOADB8(bA[0], pb); LOADB8(bA[1], pb + 8192);
            asm volatile("s_waitcnt vmcnt(16)" ::: "memory");  // bB complete
        } else {
            asm volatile("s_waitcnt vmcnt(0)" ::: "memory");
        }
        __builtin_amdgcn_sched_barrier(0);
        PASS(bB, p + 1);
    }
#undef PASS
#undef PBP

    // ---- one reduction pass: row = rt*16 + 4*g + r ----
#pragma unroll
    for (int rt = 0; rt < 8; ++rt) {
#pragma unroll
        for (int r = 0; r < 4; ++r) {
            float e = es[rt][r];
            e += __shfl_xor(e, 1);
            e += __shfl_xor(e, 2);
            e += __shfl_xor(e, 4);
            e += __shfl_xor(e, 8);
            if (rs == 0) atomicAdd(&Sbuf[rt * 16 + 4 * g + r], e);
        }
    }
    __syncthreads();
    // ---- lse over the 128 rows ----
    if (tid < 128) {
        float S = Sbuf[tid] - (float)(1024 - C1) * exp2f(-BIAS);  // exact pad removal
        float lse = (BIAS + log2f(S)) * 0.6931471805599453f;
#pragma unroll
        for (int m = 1; m < 64; m <<= 1) lse += __shfl_xor(lse, m);
        if (lane == 0) redl[tid >> 6] = lse;
    }
    __syncthreads();
    if (tid == 0) atomicAdd(&ws[WS_LSE], redl[0] + redl[1]);
}

// ---------------- proto-NCE on the means ----------------
__global__ __launch_bounds__(128, 4) void k_nce(
        const float* __restrict__ p2, const float* __restrict__ p3,
        float* __restrict__ ws) {
    __shared__ __align__(16) float mrow[256];
    __shared__ float sim[128];
    __shared__ float red[2];
    const int b = blockIdx.x;
    const float* means; const float* prot; int C, r, accIdx;
    if (b < 100) { means = ws + WS_S2; prot = p2; C = 100; r = b;       accIdx = WS_ACC2; }
    else         { means = ws + WS_S3; prot = p3; C = 20;  r = b - 100; accIdx = WS_ACC3; }
    const int tid = threadIdx.x;
    const int lane = tid & 63;
    mrow[tid]       = means[(size_t)r * 256 + tid];
    mrow[128 + tid] = means[(size_t)r * 256 + 128 + tid];
    __syncthreads();
    if (tid < C) {
        const f32x4* mr = (const f32x4*)mrow;
        const f32x4* pr = (const f32x4*)(prot + (size_t)tid * 256);
        float acc = 0.f;
#pragma unroll 4
        for (int k = 0; k < 64; ++k) {
            f32x4 m = mr[k], qv = pr[k];
            acc += m[0]*qv[0] + m[1]*qv[1] + m[2]*qv[2] + m[3]*qv[3];
        }
        sim[tid] = acc * 10.0f;
    }
    __syncthreads();
    float v = (tid < C) ? sim[tid] : -1e30f;
#pragma unroll
    for (int m = 1; m < 64; m <<= 1) v = fmaxf(v, __shfl_xor(v, m));
    if (lane == 0) red[tid >> 6] = v;
    __syncthreads();
    const float mx = fmaxf(red[0], red[1]);
    float e = (tid < C) ? __expf(sim[tid] - mx) : 0.f;
#pragma unroll
    for (int m = 1; m < 64; m <<= 1) e += __shfl_xor(e, m);
    __syncthreads();
    if (lane == 0) red[tid >> 6] = e;
    __syncthreads();
    if (tid == 0) {
        float lse = mx + logf(red[0] + red[1]);
        atomicAdd(&ws[accIdx], lse - sim[r]);
    }
}

// ---------------- finalize ----------------
__global__ void k_final(const float* __restrict__ ws, float* __restrict__ out, float Nf) {
    if (threadIdx.x == 0 && blockIdx.x == 0) {
        float fine   = (ws[WS_LSE] - 10.0f * ws[WS_POS]) / Nf;
        float coarse = ws[WS_ACC2] / 100.0f;
        float con    = ws[WS_ACC3] / 20.0f;
        out[0] = 0.5f * fine + 0.5f * coarse + 0.0f * con;
        out[1] = fine;
        out[2] = coarse;
        out[3] = con;
    }
}

extern "C" void kernel_launch(void* const* d_in, const int* in_sizes, int n_in,
                              void* d_out, int out_size, void* d_ws, size_t ws_size,
                              hipStream_t stream) {
    const float* feat = (const float*)d_in[0];
    const float* p1   = (const float*)d_in[1];
    const int*   l1   = (const int*)d_in[2];
    const float* p2   = (const float*)d_in[3];
    const int*   l2   = (const int*)d_in[4];
    const float* p3   = (const float*)d_in[5];
    const int*   l3   = (const int*)d_in[6];
    float* out = (float*)d_out;
    float* ws  = (float*)d_ws;
    const int n  = in_sizes[0] / 256;       // 131072
    const int c1 = in_sizes[1] / 256;       // 1000
    unsigned short* Pimg = (unsigned short*)((char*)d_ws + PIMG_BYTE_OFF);

    // adaptive partial-buffer count (nchunk = n/512 = 256)
    const int nchunk = n / 512;
    long nfull = ((long)(ws_size / 4) - WS_SEG) / PART_FLOATS;
    int useAtomic, npart;
    if (nfull >= nchunk) { useAtomic = 0; npart = nchunk; }
    else {
        useAtomic = 1;
        npart = 1;
        while (npart * 2 <= (int)nfull && npart < 32) npart <<= 1;
    }

    if (useAtomic)
        k_zero <<<(npart * PART_FLOATS + 255) / 256, 256, 0, stream>>>(ws + WS_SEG, npart * PART_FLOATS);
    k_prep <<<128, 256, 0, stream>>>(p1, Pimg, ws, c1);
    k_seg  <<<nchunk * 2, 256, 0, stream>>>(feat, p1, l1, l2, l3, ws, npart - 1, useAtomic);
    k_div  <<<120, 256, 0, stream>>>(ws, npart);
    k_fine <<<n / 128, 256, 0, stream>>>(feat, Pimg, ws, c1);
    k_nce  <<<120, 128, 0, stream>>>(p2, p3, ws);
    k_final<<<1, 64, 0, stream>>>(ws, out, (float)n);
}

// Round 12
// 154.429 us; speedup vs baseline: 2.1001x; 1.0454x over previous
//
#include <hip/hip_runtime.h>
#include <math.h>

// ---------------- workspace layout ----------------
#define WS_POS   0
#define WS_LSE   1
#define WS_ACC2  2
#define WS_ACC3  3
#define WS_S2    256
#define WS_S3    (256+25600)
#define WS_SEG   163840
#define NROWS    144                 // 112 padded l2 rows + 32 padded l3 rows
#define PART_FLOATS (NROWS*256 + 128)  // 36992; counts at [36864, 36984)
#define PIMG_BYTE_OFF 131072

#define SC2  14.426950408889634f    // (1/TEMP=10) * log2(e)
#define BIAS 48.0f

typedef __attribute__((ext_vector_type(4))) float f32x4;
typedef __attribute__((ext_vector_type(8))) short short8;

static __device__ __forceinline__ unsigned f2bf(float f) {
    union { float f; unsigned u; } x; x.f = f;
    unsigned r = x.u + 0x7FFFu + ((x.u >> 16) & 1u);   // RNE
    return r >> 16;
}

// ---------------- generic zero ----------------
__global__ void k_zero(float* __restrict__ p, int count) {
    int i = blockIdx.x * 256 + threadIdx.x;
    if (i < count) p[i] = 0.f;
}

// ---------------- build plain bf16 proto image [1024][256], pad rows zero ----
// (also zeroes ws[0..256) from block 0 — saves a separate launch)
__global__ void k_prep(const float* __restrict__ p1, unsigned short* __restrict__ Pimg,
                       float* __restrict__ ws, int C1) {
    if (blockIdx.x == 0) ws[threadIdx.x] = 0.f;
    int e = blockIdx.x * 256 + threadIdx.x;   // 32768 threads, 8 elems each
    int r  = e >> 5;
    int k0 = (e & 31) * 8;
    unsigned h[8];
#pragma unroll
    for (int j = 0; j < 8; ++j)
        h[j] = (r < C1) ? f2bf(p1[(size_t)r * 256 + k0 + j]) : 0u;
    uint4 v;
    v.x = h[0] | (h[1] << 16);
    v.y = h[2] | (h[3] << 16);
    v.z = h[4] | (h[5] << 16);
    v.w = h[6] | (h[7] << 16);
    *(uint4*)(Pimg + (size_t)r * 256 + k0) = v;
}

// ---- opaque B loads (r4/r7-proven): asm is not rematerializable, so loads
// issue exactly once where written and outputs stay register-resident.
#define LOADB(dst, ptr, OFF) \
    asm volatile("global_load_dwordx4 %0, %1, off offset:" #OFF \
                 : "=v"(dst) : "v"(ptr))
#define LOADB8(buf, ptr) \
    LOADB(buf[0], ptr, 0);   LOADB(buf[1], ptr, 64);  \
    LOADB(buf[2], ptr, 128); LOADB(buf[3], ptr, 192); \
    LOADB(buf[4], ptr, 256); LOADB(buf[5], ptr, 320); \
    LOADB(buf[6], ptr, 384); LOADB(buf[7], ptr, 448)

// ================= SEG body (unchanged logic; shared arrays passed in) =====
static __device__ __forceinline__ void seg_body(
        const float* __restrict__ feat, const float* __restrict__ p1,
        const int* __restrict__ l1, const int* __restrict__ l2,
        const int* __restrict__ l3, float* __restrict__ ws,
        int partMask, int useAtomic, int sblk,
        int* labs23, int* labs1, float* psum) {
    const int tid  = threadIdx.x;
    const int lane = tid & 63;
    const int wv   = tid >> 6;          // 0..3
    const int g    = lane >> 4;         // 0..3 (k-group)
    const int rs   = lane & 15;
    const int chunk = sblk >> 1, half = sblk & 1;
    const int base  = chunk * 512;
    const int dimbase = half * 128 + wv * 32;

    for (int j = tid; j < 512; j += 256) {
        labs23[j] = l2[base + j] | (l3[base + j] << 16);
        labs1[j]  = l1[base + j];
    }
    __syncthreads();

    f32x4 acc[9][2];
#pragma unroll
    for (int mt = 0; mt < 9; ++mt)
#pragma unroll
        for (int nt = 0; nt < 2; ++nt) acc[mt][nt] = (f32x4){0.f, 0.f, 0.f, 0.f};

    float fA[16], pA[16], fB[16], pB[16];
    float posacc = 0.f;

#define LOADSTEP(u, F, P) { \
    const int sl0 = (u) * 32 + 8 * g; \
    _Pragma("unroll") \
    for (int j = 0; j < 8; ++j) { \
        const int sl = sl0 + j; \
        const size_t fb = (size_t)(base + sl) * 256 + dimbase + rs; \
        F[j]     = feat[fb]; \
        F[8 + j] = feat[fb + 16]; \
        const size_t pb = (size_t)labs1[sl] * 256 + dimbase + rs; \
        P[j]     = p1[pb]; \
        P[8 + j] = p1[pb + 16]; \
    } }

#define PROCSTEP(u, F, P) { \
    _Pragma("unroll") \
    for (int j = 0; j < 16; ++j) posacc = fmaf(F[j], P[j], posacc); \
    union { unsigned w[4]; short8 s; } b0, b1; \
    _Pragma("unroll") \
    for (int q = 0; q < 4; ++q) { \
        asm("v_cvt_pk_bf16_f32 %0, %1, %2" : "=v"(b0.w[q]) : "v"(F[2*q]),   "v"(F[2*q+1])); \
        asm("v_cvt_pk_bf16_f32 %0, %1, %2" : "=v"(b1.w[q]) : "v"(F[8+2*q]), "v"(F[8+2*q+1])); \
    } \
    int d2[8], d3[8]; \
    { const int sl0 = (u) * 32 + 8 * g; \
      _Pragma("unroll") \
      for (int j = 0; j < 8; ++j) { \
          const int v = labs23[sl0 + j]; \
          d2[j] = (v & 0xffff) - rs; \
          d3[j] = (v >> 16) - rs; \
      } } \
    _Pragma("unroll") \
    for (int mt = 0; mt < 7; ++mt) { \
        union { unsigned w[4]; short8 s; } af; \
        _Pragma("unroll") \
        for (int q = 0; q < 4; ++q) { \
            unsigned w = (d2[2*q] == mt*16) ? 0x3F80u : 0u; \
            if (d2[2*q+1] == mt*16) w |= 0x3F800000u; \
            af.w[q] = w; \
        } \
        acc[mt][0] = __builtin_amdgcn_mfma_f32_16x16x32_bf16(af.s, b0.s, acc[mt][0], 0, 0, 0); \
        acc[mt][1] = __builtin_amdgcn_mfma_f32_16x16x32_bf16(af.s, b1.s, acc[mt][1], 0, 0, 0); \
    } \
    _Pragma("unroll") \
    for (int mt = 0; mt < 2; ++mt) { \
        union { unsigned w[4]; short8 s; } af; \
        _Pragma("unroll") \
        for (int q = 0; q < 4; ++q) { \
            unsigned w = (d3[2*q] == mt*16) ? 0x3F80u : 0u; \
            if (d3[2*q+1] == mt*16) w |= 0x3F800000u; \
            af.w[q] = w; \
        } \
        acc[7+mt][0] = __builtin_amdgcn_mfma_f32_16x16x32_bf16(af.s, b0.s, acc[7+mt][0], 0, 0, 0); \
        acc[7+mt][1] = __builtin_amdgcn_mfma_f32_16x16x32_bf16(af.s, b1.s, acc[7+mt][1], 0, 0, 0); \
    } }

    LOADSTEP(0, fA, pA);
#pragma unroll 1
    for (int t = 0; t < 16; t += 2) {
        LOADSTEP(t + 1, fB, pB);
        PROCSTEP(t, fA, pA);
        if (t + 2 < 16) LOADSTEP(t + 2, fA, pA);
        PROCSTEP(t + 1, fB, pB);
    }
#undef LOADSTEP
#undef PROCSTEP

    // ---- epilogue: write partials. row = mt*16 + 4*g + r, col = dim ----
    float* part = ws + WS_SEG +
        (size_t)(useAtomic ? (chunk & partMask) : chunk) * PART_FLOATS;
#pragma unroll
    for (int mt = 0; mt < 9; ++mt)
#pragma unroll
        for (int nt = 0; nt < 2; ++nt)
#pragma unroll
            for (int r = 0; r < 4; ++r) {
                float v = acc[mt][nt][r];
                float* dst = &part[(mt * 16 + 4 * g + r) * 256 + dimbase + nt * 16 + rs];
                if (useAtomic) atomicAdd(dst, v); else *dst = v;
            }

    // ---- per-class counts (half 0 only) ----
    if (half == 0 && tid < 120) {
        float cnt = 0.f;
        const int isl2 = tid < 100;
        const int cls = isl2 ? tid : tid - 100;
#pragma unroll 8
        for (int j = 0; j < 512; ++j) {
            int v = labs23[j];
            int lab = isl2 ? (v & 0xffff) : (v >> 16);
            cnt += (lab == cls) ? 1.f : 0.f;
        }
        float* dst = &part[NROWS * 256 + tid];
        if (useAtomic) atomicAdd(dst, cnt); else *dst = cnt;
    }

    // ---- reduce positive dot ----
#pragma unroll
    for (int m = 1; m < 64; m <<= 1) posacc += __shfl_xor(posacc, m);
    if (lane == 0) psum[wv] = posacc;
    __syncthreads();
    if (tid == 0) atomicAdd(&ws[WS_POS], psum[0] + psum[1] + psum[2] + psum[3]);
}

// ================= FINE body (r7 structure, unchanged logic) ===============
static __device__ __forceinline__ void fine_body(
        const float* __restrict__ feat, const unsigned short* __restrict__ Pimg,
        float* __restrict__ ws, int C1, int fblk,
        unsigned short* Af, float* Sbuf, float* redl) {
    const int tid  = threadIdx.x;
    const int lane = tid & 63;
    const int wv   = tid >> 6;        // 0..3
    const int g    = lane >> 4;       // 0..3
    const int rs   = lane & 15;
    const int row0 = fblk * 128;

#define PBP(p) ((const char*)Pimg + (size_t)((p) * 128 + wv * 32 + rs) * 512 + g * 16)

    // ---- issue pass-0 B loads first: they complete under the staging ----
    short8 bA[2][8], bB[2][8];
    { const char* pb = PBP(0); LOADB8(bA[0], pb); LOADB8(bA[1], pb + 8192); }

    // ---- stage A: 8 floats/unit -> cvt_pk x4 -> ds_write_b128, swizzled ----
#pragma unroll
    for (int i = 0; i < 16; ++i) {
        int u = tid + i * 256;                 // 16B unit, 4096 total
        int r = u >> 5, q8 = u & 31;
        const float* src = feat + (size_t)(row0 + r) * 256 + q8 * 8;
        f32x4 v0 = *(const f32x4*)(src);
        f32x4 v1 = *(const f32x4*)(src + 4);
        uint4 pk;
        asm("v_cvt_pk_bf16_f32 %0, %1, %2" : "=v"(pk.x) : "v"(v0[0]), "v"(v0[1]));
        asm("v_cvt_pk_bf16_f32 %0, %1, %2" : "=v"(pk.y) : "v"(v0[2]), "v"(v0[3]));
        asm("v_cvt_pk_bf16_f32 %0, %1, %2" : "=v"(pk.z) : "v"(v1[0]), "v"(v1[1]));
        asm("v_cvt_pk_bf16_f32 %0, %1, %2" : "=v"(pk.w) : "v"(v1[2]), "v"(v1[3]));
        *(uint4*)((char*)Af + r * 512 + ((q8 * 16) ^ ((r & 7) << 4))) = pk;
    }
    if (tid < 128) Sbuf[tid] = 0.f;
    __syncthreads();   // compiler drains vmcnt here -> bA valid after barrier

    float es[8][4];
#pragma unroll
    for (int a = 0; a < 8; ++a)
#pragma unroll
        for (int b = 0; b < 4; ++b) es[a][b] = 0.f;

#define PASS(BUF, pp) { \
    _Pragma("unroll") \
    for (int rt = 0; rt < 8; ++rt) { \
        f32x4 acc0 = (f32x4){0.f, 0.f, 0.f, 0.f}; \
        f32x4 acc1 = (f32x4){0.f, 0.f, 0.f, 0.f}; \
        const int ar = rt * 16 + rs; \
        const char* abase = (const char*)Af + ar * 512; \
        const int sw = (ar & 7) << 4; \
        _Pragma("unroll") \
        for (int ks = 0; ks < 8; ++ks) { \
            short8 a = *(const short8*)(abase + ((ks * 64 + g * 16) ^ sw)); \
            acc0 = __builtin_amdgcn_mfma_f32_16x16x32_bf16(a, BUF[0][ks], acc0, 0, 0, 0); \
            acc1 = __builtin_amdgcn_mfma_f32_16x16x32_bf16(a, BUF[1][ks], acc1, 0, 0, 0); \
        } \
        _Pragma("unroll") \
        for (int r = 0; r < 4; ++r) { \
            float t0 = fmaf(acc0[r], SC2, -BIAS); \
            float t1 = fmaf(acc1[r], SC2, -BIAS); \
            float e0, e1; \
            asm("v_exp_f32 %0, %2\n\t" \
                "v_exp_f32 %1, %3\n\t" \
                "s_nop 1" \
                : "=&v"(e0), "=&v"(e1) : "v"(t0), "v"(t1)); \
            es[rt][r] += e0 + e1; \
        } \
    } }

#pragma unroll 1
    for (int p = 0; p < 8; p += 2) {
        // prefetch pass p+1 into bB, then compute pass p from bA
        { const char* pb = PBP(p + 1); LOADB8(bB[0], pb); LOADB8(bB[1], pb + 8192); }
        asm volatile("s_waitcnt vmcnt(16)" ::: "memory");   // bA complete
        __builtin_amdgcn_sched_barrier(0);
        PASS(bA, p);
        // prefetch pass p+2 into bA (if any), then compute pass p+1 from bB
        if (p + 2 < 8) {
            const char* pb = PBP(p + 2); LOADB8(bA[0], pb); LOADB8(bA[1], pb + 8192);
            asm volatile("s_waitcnt vmcnt(16)" ::: "memory");  // bB complete
        } else {
            asm volatile("s_waitcnt vmcnt(0)" ::: "memory");
        }
        __builtin_amdgcn_sched_barrier(0);
        PASS(bB, p + 1);
    }
#undef PASS
#undef PBP

    // ---- one reduction pass: row = rt*16 + 4*g + r ----
#pragma unroll
    for (int rt = 0; rt < 8; ++rt) {
#pragma unroll
        for (int r = 0; r < 4; ++r) {
            float e = es[rt][r];
            e += __shfl_xor(e, 1);
            e += __shfl_xor(e, 2);
            e += __shfl_xor(e, 4);
            e += __shfl_xor(e, 8);
            if (rs == 0) atomicAdd(&Sbuf[rt * 16 + 4 * g + r], e);
        }
    }
    __syncthreads();
    // ---- lse over the 128 rows ----
    if (tid < 128) {
        float S = Sbuf[tid] - (float)(1024 - C1) * exp2f(-BIAS);  // exact pad removal
        float lse = (BIAS + log2f(S)) * 0.6931471805599453f;
#pragma unroll
        for (int m = 1; m < 64; m <<= 1) lse += __shfl_xor(lse, m);
        if (lane == 0) redl[tid >> 6] = lse;
    }
    __syncthreads();
    if (tid == 0) atomicAdd(&ws[WS_LSE], redl[0] + redl[1]);
}

// ============ MERGED kernel: seg + fine co-resident on each CU =============
// k_seg (~45 us) and k_fine (~98.5 us) are data-independent and BOTH
// stall-dominated (every pipe <30% busy, r0-r11 ledger). Block-role
// dispatch (bid%3==0 -> seg, else fine; nfine = 2*nseg exactly) makes each
// CU's 2 resident blocks a seg/fine mix, so one workload's dependency
// stalls are filled by the other's ready work (m114: MFMA-pipe and
// VALU-pipe waves on one CU co-schedule at ~max, not sum). Seg's small
// shared arrays alias into Af; LDS stays 66.5 KB -> 2 blocks/CU.
__global__ __launch_bounds__(256, 2) void k_merged(
        const float* __restrict__ feat, const float* __restrict__ p1,
        const unsigned short* __restrict__ Pimg,
        const int* __restrict__ l1, const int* __restrict__ l2,
        const int* __restrict__ l3, float* __restrict__ ws,
        int C1, int partMask, int useAtomic) {
    __shared__ __align__(16) unsigned short Af[128 * 256];  // 64 KB
    __shared__ float Sbuf[128];
    __shared__ float redl[2];
    const int bid = blockIdx.x;
    if (bid % 3 == 0) {
        // seg role: aliases carved from Af (4 KB) + Sbuf (16 B)
        seg_body(feat, p1, l1, l2, l3, ws, partMask, useAtomic, bid / 3,
                 (int*)Af, (int*)(Af + 1024), Sbuf);
    } else {
        fine_body(feat, Pimg, ws, C1, (bid - 1) - (bid - 1) / 3,
                  Af, Sbuf, redl);
    }
}

// ---------------- partials -> means (one block per class row) ----------------
__global__ __launch_bounds__(256, 4) void k_div(float* __restrict__ ws, int npart) {
    __shared__ float cred[4];
    const int c = blockIdx.x;             // 0..119
    const int d = threadIdx.x;            // dim
    const int prow = (c < 100) ? c : 112 + (c - 100);
    float cv = (d < npart) ? ws[WS_SEG + (size_t)d * PART_FLOATS + NROWS * 256 + c] : 0.f;
#pragma unroll
    for (int m = 1; m < 64; m <<= 1) cv += __shfl_xor(cv, m);
    if ((d & 63) == 0) cred[d >> 6] = cv;
    __syncthreads();
    const float cnt = cred[0] + cred[1] + cred[2] + cred[3];
    float a0=0,a1=0,a2=0,a3=0,a4=0,a5=0,a6=0,a7=0;
    int p = 0;
    for (; p + 8 <= npart; p += 8) {
        const float* b = ws + WS_SEG + (size_t)p * PART_FLOATS + prow * 256 + d;
        a0 += b[0 * (size_t)PART_FLOATS];
        a1 += b[1 * (size_t)PART_FLOATS];
        a2 += b[2 * (size_t)PART_FLOATS];
        a3 += b[3 * (size_t)PART_FLOATS];
        a4 += b[4 * (size_t)PART_FLOATS];
        a5 += b[5 * (size_t)PART_FLOATS];
        a6 += b[6 * (size_t)PART_FLOATS];
        a7 += b[7 * (size_t)PART_FLOATS];
    }
    for (; p < npart; ++p)
        a0 += ws[WS_SEG + (size_t)p * PART_FLOATS + prow * 256 + d];
    const float s = ((a0+a1)+(a2+a3)) + ((a4+a5)+(a6+a7));
    ws[256 + ((c < 100) ? c * 256 : 25600 + (c - 100) * 256) + d] = s / cnt;
}

// ---------------- proto-NCE on the means ----------------
__global__ __launch_bounds__(128, 4) void k_nce(
        const float* __restrict__ p2, const float* __restrict__ p3,
        float* __restrict__ ws) {
    __shared__ __align__(16) float mrow[256];
    __shared__ float sim[128];
    __shared__ float red[2];
    const int b = blockIdx.x;
    const float* means; const float* prot; int C, r, accIdx;
    if (b < 100) { means = ws + WS_S2; prot = p2; C = 100; r = b;       accIdx = WS_ACC2; }
    else         { means = ws + WS_S3; prot = p3; C = 20;  r = b - 100; accIdx = WS_ACC3; }
    const int tid = threadIdx.x;
    const int lane = tid & 63;
    mrow[tid]       = means[(size_t)r * 256 + tid];
    mrow[128 + tid] = means[(size_t)r * 256 + 128 + tid];
    __syncthreads();
    if (tid < C) {
        const f32x4* mr = (const f32x4*)mrow;
        const f32x4* pr = (const f32x4*)(prot + (size_t)tid * 256);
        float acc = 0.f;
#pragma unroll 4
        for (int k = 0; k < 64; ++k) {
            f32x4 m = mr[k], qv = pr[k];
            acc += m[0]*qv[0] + m[1]*qv[1] + m[2]*qv[2] + m[3]*qv[3];
        }
        sim[tid] = acc * 10.0f;
    }
    __syncthreads();
    float v = (tid < C) ? sim[tid] : -1e30f;
#pragma unroll
    for (int m = 1; m < 64; m <<= 1) v = fmaxf(v, __shfl_xor(v, m));
    if (lane == 0) red[tid >> 6] = v;
    __syncthreads();
    const float mx = fmaxf(red[0], red[1]);
    float e = (tid < C) ? __expf(sim[tid] - mx) : 0.f;
#pragma unroll
    for (int m = 1; m < 64; m <<= 1) e += __shfl_xor(e, m);
    __syncthreads();
    if (lane == 0) red[tid >> 6] = e;
    __syncthreads();
    if (tid == 0) {
        float lse = mx + logf(red[0] + red[1]);
        atomicAdd(&ws[accIdx], lse - sim[r]);
    }
}

// ---------------- finalize ----------------
__global__ void k_final(const float* __restrict__ ws, float* __restrict__ out, float Nf) {
    if (threadIdx.x == 0 && blockIdx.x == 0) {
        float fine   = (ws[WS_LSE] - 10.0f * ws[WS_POS]) / Nf;
        float coarse = ws[WS_ACC2] / 100.0f;
        float con    = ws[WS_ACC3] / 20.0f;
        out[0] = 0.5f * fine + 0.5f * coarse + 0.0f * con;
        out[1] = fine;
        out[2] = coarse;
        out[3] = con;
    }
}

extern "C" void kernel_launch(void* const* d_in, const int* in_sizes, int n_in,
                              void* d_out, int out_size, void* d_ws, size_t ws_size,
                              hipStream_t stream) {
    const float* feat = (const float*)d_in[0];
    const float* p1   = (const float*)d_in[1];
    const int*   l1   = (const int*)d_in[2];
    const float* p2   = (const float*)d_in[3];
    const int*   l2   = (const int*)d_in[4];
    const float* p3   = (const float*)d_in[5];
    const int*   l3   = (const int*)d_in[6];
    float* out = (float*)d_out;
    float* ws  = (float*)d_ws;
    const int n  = in_sizes[0] / 256;       // 131072
    const int c1 = in_sizes[1] / 256;       // 1000
    unsigned short* Pimg = (unsigned short*)((char*)d_ws + PIMG_BYTE_OFF);

    // adaptive partial-buffer count (nchunk = n/512 = 256)
    const int nchunk = n / 512;
    long nfull = ((long)(ws_size / 4) - WS_SEG) / PART_FLOATS;
    int useAtomic, npart;
    if (nfull >= nchunk) { useAtomic = 0; npart = nchunk; }
    else {
        useAtomic = 1;
        npart = 1;
        while (npart * 2 <= (int)nfull && npart < 32) npart <<= 1;
    }

    if (useAtomic)
        k_zero <<<(npart * PART_FLOATS + 255) / 256, 256, 0, stream>>>(ws + WS_SEG, npart * PART_FLOATS);
    k_prep <<<128, 256, 0, stream>>>(p1, Pimg, ws, c1);
    // merged seg+fine: nseg = nchunk*2, nfine = n/128 = 2*nseg, grid = 3*nseg
    k_merged <<<nchunk * 6, 256, 0, stream>>>(feat, p1, Pimg, l1, l2, l3, ws,
                                              c1, npart - 1, useAtomic);
    k_div  <<<120, 256, 0, stream>>>(ws, npart);
    k_nce  <<<120, 128, 0, stream>>>(p2, p3, ws);
    k_final<<<1, 64, 0, stream>>>(ws, out, (float)n);
}

// Round 13
// 152.179 us; speedup vs baseline: 2.1311x; 1.0148x over previous
//
#include <hip/hip_runtime.h>
#include <math.h>

// ---------------- workspace layout ----------------
#define WS_POS   0
#define WS_LSE   1
#define WS_ACC2  2
#define WS_ACC3  3
#define WS_SEG   163840
#define NROWS    144                 // 112 padded l2 rows + 32 padded l3 rows
#define PART_FLOATS (NROWS*256 + 128)  // 36992; counts at [36864, 36984)
#define PIMG_BYTE_OFF 131072

#define SC2  14.426950408889634f    // (1/TEMP=10) * log2(e)
#define BIAS 48.0f

typedef __attribute__((ext_vector_type(4))) float f32x4;
typedef __attribute__((ext_vector_type(8))) short short8;

static __device__ __forceinline__ unsigned f2bf(float f) {
    union { float f; unsigned u; } x; x.f = f;
    unsigned r = x.u + 0x7FFFu + ((x.u >> 16) & 1u);   // RNE
    return r >> 16;
}

// ---------------- generic zero ----------------
__global__ void k_zero(float* __restrict__ p, int count) {
    int i = blockIdx.x * 256 + threadIdx.x;
    if (i < count) p[i] = 0.f;
}

// ---------------- build plain bf16 proto image [1024][256], pad rows zero ----
// (also zeroes ws[0..256) from block 0 — saves a separate launch)
__global__ void k_prep(const float* __restrict__ p1, unsigned short* __restrict__ Pimg,
                       float* __restrict__ ws, int C1) {
    if (blockIdx.x == 0) ws[threadIdx.x] = 0.f;
    int e = blockIdx.x * 256 + threadIdx.x;   // 32768 threads, 8 elems each
    int r  = e >> 5;
    int k0 = (e & 31) * 8;
    unsigned h[8];
#pragma unroll
    for (int j = 0; j < 8; ++j)
        h[j] = (r < C1) ? f2bf(p1[(size_t)r * 256 + k0 + j]) : 0u;
    uint4 v;
    v.x = h[0] | (h[1] << 16);
    v.y = h[2] | (h[3] << 16);
    v.z = h[4] | (h[5] << 16);
    v.w = h[6] | (h[7] << 16);
    *(uint4*)(Pimg + (size_t)r * 256 + k0) = v;
}

// ---- opaque B loads (r4/r7-proven): asm is not rematerializable, so loads
// issue exactly once where written and outputs stay register-resident.
#define LOADB(dst, ptr, OFF) \
    asm volatile("global_load_dwordx4 %0, %1, off offset:" #OFF \
                 : "=v"(dst) : "v"(ptr))
#define LOADB8(buf, ptr) \
    LOADB(buf[0], ptr, 0);   LOADB(buf[1], ptr, 64);  \
    LOADB(buf[2], ptr, 128); LOADB(buf[3], ptr, 192); \
    LOADB(buf[4], ptr, 256); LOADB(buf[5], ptr, 320); \
    LOADB(buf[6], ptr, 384); LOADB(buf[7], ptr, 448)

// ================= SEG body (unchanged logic; shared arrays passed in) =====
static __device__ __forceinline__ void seg_body(
        const float* __restrict__ feat, const float* __restrict__ p1,
        const int* __restrict__ l1, const int* __restrict__ l2,
        const int* __restrict__ l3, float* __restrict__ ws,
        int partMask, int useAtomic, int sblk,
        int* labs23, int* labs1, float* psum) {
    const int tid  = threadIdx.x;
    const int lane = tid & 63;
    const int wv   = tid >> 6;          // 0..3
    const int g    = lane >> 4;         // 0..3 (k-group)
    const int rs   = lane & 15;
    const int chunk = sblk >> 1, half = sblk & 1;
    const int base  = chunk * 512;
    const int dimbase = half * 128 + wv * 32;

    for (int j = tid; j < 512; j += 256) {
        labs23[j] = l2[base + j] | (l3[base + j] << 16);
        labs1[j]  = l1[base + j];
    }
    __syncthreads();

    f32x4 acc[9][2];
#pragma unroll
    for (int mt = 0; mt < 9; ++mt)
#pragma unroll
        for (int nt = 0; nt < 2; ++nt) acc[mt][nt] = (f32x4){0.f, 0.f, 0.f, 0.f};

    float fA[16], pA[16], fB[16], pB[16];
    float posacc = 0.f;

#define LOADSTEP(u, F, P) { \
    const int sl0 = (u) * 32 + 8 * g; \
    _Pragma("unroll") \
    for (int j = 0; j < 8; ++j) { \
        const int sl = sl0 + j; \
        const size_t fb = (size_t)(base + sl) * 256 + dimbase + rs; \
        F[j]     = feat[fb]; \
        F[8 + j] = feat[fb + 16]; \
        const size_t pb = (size_t)labs1[sl] * 256 + dimbase + rs; \
        P[j]     = p1[pb]; \
        P[8 + j] = p1[pb + 16]; \
    } }

#define PROCSTEP(u, F, P) { \
    _Pragma("unroll") \
    for (int j = 0; j < 16; ++j) posacc = fmaf(F[j], P[j], posacc); \
    union { unsigned w[4]; short8 s; } b0, b1; \
    _Pragma("unroll") \
    for (int q = 0; q < 4; ++q) { \
        asm("v_cvt_pk_bf16_f32 %0, %1, %2" : "=v"(b0.w[q]) : "v"(F[2*q]),   "v"(F[2*q+1])); \
        asm("v_cvt_pk_bf16_f32 %0, %1, %2" : "=v"(b1.w[q]) : "v"(F[8+2*q]), "v"(F[8+2*q+1])); \
    } \
    int d2[8], d3[8]; \
    { const int sl0 = (u) * 32 + 8 * g; \
      _Pragma("unroll") \
      for (int j = 0; j < 8; ++j) { \
          const int v = labs23[sl0 + j]; \
          d2[j] = (v & 0xffff) - rs; \
          d3[j] = (v >> 16) - rs; \
      } } \
    _Pragma("unroll") \
    for (int mt = 0; mt < 7; ++mt) { \
        union { unsigned w[4]; short8 s; } af; \
        _Pragma("unroll") \
        for (int q = 0; q < 4; ++q) { \
            unsigned w = (d2[2*q] == mt*16) ? 0x3F80u : 0u; \
            if (d2[2*q+1] == mt*16) w |= 0x3F800000u; \
            af.w[q] = w; \
        } \
        acc[mt][0] = __builtin_amdgcn_mfma_f32_16x16x32_bf16(af.s, b0.s, acc[mt][0], 0, 0, 0); \
        acc[mt][1] = __builtin_amdgcn_mfma_f32_16x16x32_bf16(af.s, b1.s, acc[mt][1], 0, 0, 0); \
    } \
    _Pragma("unroll") \
    for (int mt = 0; mt < 2; ++mt) { \
        union { unsigned w[4]; short8 s; } af; \
        _Pragma("unroll") \
        for (int q = 0; q < 4; ++q) { \
            unsigned w = (d3[2*q] == mt*16) ? 0x3F80u : 0u; \
            if (d3[2*q+1] == mt*16) w |= 0x3F800000u; \
            af.w[q] = w; \
        } \
        acc[7+mt][0] = __builtin_amdgcn_mfma_f32_16x16x32_bf16(af.s, b0.s, acc[7+mt][0], 0, 0, 0); \
        acc[7+mt][1] = __builtin_amdgcn_mfma_f32_16x16x32_bf16(af.s, b1.s, acc[7+mt][1], 0, 0, 0); \
    } }

    LOADSTEP(0, fA, pA);
#pragma unroll 1
    for (int t = 0; t < 16; t += 2) {
        LOADSTEP(t + 1, fB, pB);
        PROCSTEP(t, fA, pA);
        if (t + 2 < 16) LOADSTEP(t + 2, fA, pA);
        PROCSTEP(t + 1, fB, pB);
    }
#undef LOADSTEP
#undef PROCSTEP

    // ---- epilogue: write partials. row = mt*16 + 4*g + r, col = dim ----
    float* part = ws + WS_SEG +
        (size_t)(useAtomic ? (chunk & partMask) : chunk) * PART_FLOATS;
#pragma unroll
    for (int mt = 0; mt < 9; ++mt)
#pragma unroll
        for (int nt = 0; nt < 2; ++nt)
#pragma unroll
            for (int r = 0; r < 4; ++r) {
                float v = acc[mt][nt][r];
                float* dst = &part[(mt * 16 + 4 * g + r) * 256 + dimbase + nt * 16 + rs];
                if (useAtomic) atomicAdd(dst, v); else *dst = v;
            }

    // ---- per-class counts (half 0 only) ----
    if (half == 0 && tid < 120) {
        float cnt = 0.f;
        const int isl2 = tid < 100;
        const int cls = isl2 ? tid : tid - 100;
#pragma unroll 8
        for (int j = 0; j < 512; ++j) {
            int v = labs23[j];
            int lab = isl2 ? (v & 0xffff) : (v >> 16);
            cnt += (lab == cls) ? 1.f : 0.f;
        }
        float* dst = &part[NROWS * 256 + tid];
        if (useAtomic) atomicAdd(dst, cnt); else *dst = cnt;
    }

    // ---- reduce positive dot ----
#pragma unroll
    for (int m = 1; m < 64; m <<= 1) posacc += __shfl_xor(posacc, m);
    if (lane == 0) psum[wv] = posacc;
    __syncthreads();
    if (tid == 0) atomicAdd(&ws[WS_POS], psum[0] + psum[1] + psum[2] + psum[3]);
}

// ================= FINE body (r7 structure, unchanged logic) ===============
static __device__ __forceinline__ void fine_body(
        const float* __restrict__ feat, const unsigned short* __restrict__ Pimg,
        float* __restrict__ ws, int C1, int fblk,
        unsigned short* Af, float* Sbuf, float* redl) {
    const int tid  = threadIdx.x;
    const int lane = tid & 63;
    const int wv   = tid >> 6;        // 0..3
    const int g    = lane >> 4;       // 0..3
    const int rs   = lane & 15;
    const int row0 = fblk * 128;

#define PBP(p) ((const char*)Pimg + (size_t)((p) * 128 + wv * 32 + rs) * 512 + g * 16)

    // ---- issue pass-0 B loads first: they complete under the staging ----
    short8 bA[2][8], bB[2][8];
    { const char* pb = PBP(0); LOADB8(bA[0], pb); LOADB8(bA[1], pb + 8192); }

    // ---- stage A: 8 floats/unit -> cvt_pk x4 -> ds_write_b128, swizzled ----
#pragma unroll
    for (int i = 0; i < 16; ++i) {
        int u = tid + i * 256;                 // 16B unit, 4096 total
        int r = u >> 5, q8 = u & 31;
        const float* src = feat + (size_t)(row0 + r) * 256 + q8 * 8;
        f32x4 v0 = *(const f32x4*)(src);
        f32x4 v1 = *(const f32x4*)(src + 4);
        uint4 pk;
        asm("v_cvt_pk_bf16_f32 %0, %1, %2" : "=v"(pk.x) : "v"(v0[0]), "v"(v0[1]));
        asm("v_cvt_pk_bf16_f32 %0, %1, %2" : "=v"(pk.y) : "v"(v0[2]), "v"(v0[3]));
        asm("v_cvt_pk_bf16_f32 %0, %1, %2" : "=v"(pk.z) : "v"(v1[0]), "v"(v1[1]));
        asm("v_cvt_pk_bf16_f32 %0, %1, %2" : "=v"(pk.w) : "v"(v1[2]), "v"(v1[3]));
        *(uint4*)((char*)Af + r * 512 + ((q8 * 16) ^ ((r & 7) << 4))) = pk;
    }
    if (tid < 128) Sbuf[tid] = 0.f;
    __syncthreads();   // compiler drains vmcnt here -> bA valid after barrier

    float es[8][4];
#pragma unroll
    for (int a = 0; a < 8; ++a)
#pragma unroll
        for (int b = 0; b < 4; ++b) es[a][b] = 0.f;

#define PASS(BUF, pp) { \
    _Pragma("unroll") \
    for (int rt = 0; rt < 8; ++rt) { \
        f32x4 acc0 = (f32x4){0.f, 0.f, 0.f, 0.f}; \
        f32x4 acc1 = (f32x4){0.f, 0.f, 0.f, 0.f}; \
        const int ar = rt * 16 + rs; \
        const char* abase = (const char*)Af + ar * 512; \
        const int sw = (ar & 7) << 4; \
        _Pragma("unroll") \
        for (int ks = 0; ks < 8; ++ks) { \
            short8 a = *(const short8*)(abase + ((ks * 64 + g * 16) ^ sw)); \
            acc0 = __builtin_amdgcn_mfma_f32_16x16x32_bf16(a, BUF[0][ks], acc0, 0, 0, 0); \
            acc1 = __builtin_amdgcn_mfma_f32_16x16x32_bf16(a, BUF[1][ks], acc1, 0, 0, 0); \
        } \
        _Pragma("unroll") \
        for (int r = 0; r < 4; ++r) { \
            float t0 = fmaf(acc0[r], SC2, -BIAS); \
            float t1 = fmaf(acc1[r], SC2, -BIAS); \
            float e0, e1; \
            asm("v_exp_f32 %0, %2\n\t" \
                "v_exp_f32 %1, %3\n\t" \
                "s_nop 1" \
                : "=&v"(e0), "=&v"(e1) : "v"(t0), "v"(t1)); \
            es[rt][r] += e0 + e1; \
        } \
    } }

#pragma unroll 1
    for (int p = 0; p < 8; p += 2) {
        // prefetch pass p+1 into bB, then compute pass p from bA
        { const char* pb = PBP(p + 1); LOADB8(bB[0], pb); LOADB8(bB[1], pb + 8192); }
        asm volatile("s_waitcnt vmcnt(16)" ::: "memory");   // bA complete
        __builtin_amdgcn_sched_barrier(0);
        PASS(bA, p);
        // prefetch pass p+2 into bA (if any), then compute pass p+1 from bB
        if (p + 2 < 8) {
            const char* pb = PBP(p + 2); LOADB8(bA[0], pb); LOADB8(bA[1], pb + 8192);
            asm volatile("s_waitcnt vmcnt(16)" ::: "memory");  // bB complete
        } else {
            asm volatile("s_waitcnt vmcnt(0)" ::: "memory");
        }
        __builtin_amdgcn_sched_barrier(0);
        PASS(bB, p + 1);
    }
#undef PASS
#undef PBP

    // ---- one reduction pass: row = rt*16 + 4*g + r ----
#pragma unroll
    for (int rt = 0; rt < 8; ++rt) {
#pragma unroll
        for (int r = 0; r < 4; ++r) {
            float e = es[rt][r];
            e += __shfl_xor(e, 1);
            e += __shfl_xor(e, 2);
            e += __shfl_xor(e, 4);
            e += __shfl_xor(e, 8);
            if (rs == 0) atomicAdd(&Sbuf[rt * 16 + 4 * g + r], e);
        }
    }
    __syncthreads();
    // ---- lse over the 128 rows ----
    if (tid < 128) {
        float S = Sbuf[tid] - (float)(1024 - C1) * exp2f(-BIAS);  // exact pad removal
        float lse = (BIAS + log2f(S)) * 0.6931471805599453f;
#pragma unroll
        for (int m = 1; m < 64; m <<= 1) lse += __shfl_xor(lse, m);
        if (lane == 0) redl[tid >> 6] = lse;
    }
    __syncthreads();
    if (tid == 0) atomicAdd(&ws[WS_LSE], redl[0] + redl[1]);
}

// ============ MERGED kernel: seg + fine co-resident on each CU =============
// r12-measured: total 161.4 -> 154.4 us (win from removing the dispatch
// boundary; per-block interference ~5%, no deeper overlap). Unchanged.
__global__ __launch_bounds__(256, 2) void k_merged(
        const float* __restrict__ feat, const float* __restrict__ p1,
        const unsigned short* __restrict__ Pimg,
        const int* __restrict__ l1, const int* __restrict__ l2,
        const int* __restrict__ l3, float* __restrict__ ws,
        int C1, int partMask, int useAtomic) {
    __shared__ __align__(16) unsigned short Af[128 * 256];  // 64 KB
    __shared__ float Sbuf[128];
    __shared__ float redl[2];
    const int bid = blockIdx.x;
    if (bid % 3 == 0) {
        // seg role: aliases carved from Af (4 KB) + Sbuf (16 B)
        seg_body(feat, p1, l1, l2, l3, ws, partMask, useAtomic, bid / 3,
                 (int*)Af, (int*)(Af + 1024), Sbuf);
    } else {
        fine_body(feat, Pimg, ws, C1, (bid - 1) - (bid - 1) / 3,
                  Af, Sbuf, redl);
    }
}

// ---- fused partials->mean + proto-NCE (one block per class row) ----------
// k_nce block b consumed exactly the mean row k_div block b produced, so
// the two fuse: mean stays in LDS (no global round-trip), one launch less.
__global__ __launch_bounds__(256, 4) void k_divnce(
        const float* __restrict__ p2, const float* __restrict__ p3,
        float* __restrict__ ws, int npart) {
    __shared__ float cred[4];
    __shared__ __align__(16) float mrow[256];
    __shared__ float sims[128];
    __shared__ float red[4];
    const int c = blockIdx.x;             // 0..119
    const int d = threadIdx.x;            // dim / proto index
    const int lane = d & 63;
    const int prow = (c < 100) ? c : 112 + (c - 100);

    // ---- phase 1: per-class count ----
    float cv = (d < npart) ? ws[WS_SEG + (size_t)d * PART_FLOATS + NROWS * 256 + c] : 0.f;
#pragma unroll
    for (int m = 1; m < 64; m <<= 1) cv += __shfl_xor(cv, m);
    if (lane == 0) cred[d >> 6] = cv;
    __syncthreads();
    const float cnt = cred[0] + cred[1] + cred[2] + cred[3];

    // ---- phase 2: sum partials -> mean row (to LDS, not global) ----
    float a0=0,a1=0,a2=0,a3=0,a4=0,a5=0,a6=0,a7=0;
    int p = 0;
    for (; p + 8 <= npart; p += 8) {
        const float* b = ws + WS_SEG + (size_t)p * PART_FLOATS + prow * 256 + d;
        a0 += b[0 * (size_t)PART_FLOATS];
        a1 += b[1 * (size_t)PART_FLOATS];
        a2 += b[2 * (size_t)PART_FLOATS];
        a3 += b[3 * (size_t)PART_FLOATS];
        a4 += b[4 * (size_t)PART_FLOATS];
        a5 += b[5 * (size_t)PART_FLOATS];
        a6 += b[6 * (size_t)PART_FLOATS];
        a7 += b[7 * (size_t)PART_FLOATS];
    }
    for (; p < npart; ++p)
        a0 += ws[WS_SEG + (size_t)p * PART_FLOATS + prow * 256 + d];
    const float s = ((a0+a1)+(a2+a3)) + ((a4+a5)+(a6+a7));
    mrow[d] = s / cnt;
    __syncthreads();

    // ---- phase 3: NCE row c against its prototype set ----
    const float* prot; int C, r, accIdx;
    if (c < 100) { prot = p2; C = 100; r = c;       accIdx = WS_ACC2; }
    else         { prot = p3; C = 20;  r = c - 100; accIdx = WS_ACC3; }
    float simv = 0.f;
    if (d < C) {
        const f32x4* mr = (const f32x4*)mrow;
        const f32x4* pr = (const f32x4*)(prot + (size_t)d * 256);
        float acc = 0.f;
#pragma unroll 4
        for (int k = 0; k < 64; ++k) {
            f32x4 m = mr[k], qv = pr[k];
            acc += m[0]*qv[0] + m[1]*qv[1] + m[2]*qv[2] + m[3]*qv[3];
        }
        simv = acc * 10.0f;
        sims[d] = simv;
    }
    __syncthreads();
    float v = (d < C) ? simv : -1e30f;
#pragma unroll
    for (int m = 1; m < 64; m <<= 1) v = fmaxf(v, __shfl_xor(v, m));
    if (lane == 0) red[d >> 6] = v;
    __syncthreads();
    const float mx = fmaxf(fmaxf(red[0], red[1]), fmaxf(red[2], red[3]));
    float e = (d < C) ? __expf(simv - mx) : 0.f;
#pragma unroll
    for (int m = 1; m < 64; m <<= 1) e += __shfl_xor(e, m);
    __syncthreads();
    if (lane == 0) red[d >> 6] = e;
    __syncthreads();
    if (d == 0) {
        float tot = (red[0] + red[1]) + (red[2] + red[3]);
        float lse = mx + logf(tot);
        atomicAdd(&ws[accIdx], lse - sims[r]);
    }
}

// ---------------- finalize ----------------
__global__ void k_final(const float* __restrict__ ws, float* __restrict__ out, float Nf) {
    if (threadIdx.x == 0 && blockIdx.x == 0) {
        float fine   = (ws[WS_LSE] - 10.0f * ws[WS_POS]) / Nf;
        float coarse = ws[WS_ACC2] / 100.0f;
        float con    = ws[WS_ACC3] / 20.0f;
        out[0] = 0.5f * fine + 0.5f * coarse + 0.0f * con;
        out[1] = fine;
        out[2] = coarse;
        out[3] = con;
    }
}

extern "C" void kernel_launch(void* const* d_in, const int* in_sizes, int n_in,
                              void* d_out, int out_size, void* d_ws, size_t ws_size,
                              hipStream_t stream) {
    const float* feat = (const float*)d_in[0];
    const float* p1   = (const float*)d_in[1];
    const int*   l1   = (const int*)d_in[2];
    const float* p2   = (const float*)d_in[3];
    const int*   l2   = (const int*)d_in[4];
    const float* p3   = (const float*)d_in[5];
    const int*   l3   = (const int*)d_in[6];
    float* out = (float*)d_out;
    float* ws  = (float*)d_ws;
    const int n  = in_sizes[0] / 256;       // 131072
    const int c1 = in_sizes[1] / 256;       // 1000
    unsigned short* Pimg = (unsigned short*)((char*)d_ws + PIMG_BYTE_OFF);

    // adaptive partial-buffer count (nchunk = n/512 = 256)
    const int nchunk = n / 512;
    long nfull = ((long)(ws_size / 4) - WS_SEG) / PART_FLOATS;
    int useAtomic, npart;
    if (nfull >= nchunk) { useAtomic = 0; npart = nchunk; }
    else {
        useAtomic = 1;
        npart = 1;
        while (npart * 2 <= (int)nfull && npart < 32) npart <<= 1;
    }

    if (useAtomic)
        k_zero <<<(npart * PART_FLOATS + 255) / 256, 256, 0, stream>>>(ws + WS_SEG, npart * PART_FLOATS);
    k_prep <<<128, 256, 0, stream>>>(p1, Pimg, ws, c1);
    // merged seg+fine: nseg = nchunk*2, nfine = n/128 = 2*nseg, grid = 3*nseg
    k_merged <<<nchunk * 6, 256, 0, stream>>>(feat, p1, Pimg, l1, l2, l3, ws,
                                              c1, npart - 1, useAtomic);
    k_divnce <<<120, 256, 0, stream>>>(p2, p3, ws, npart);
    k_final<<<1, 64, 0, stream>>>(ws, out, (float)n);
}